// Round 1
// baseline (14739.751 us; speedup 1.0000x reference)
//
#include <hip/hip_runtime.h>
#include <hip/hip_bf16.h>
#include <cstdint>
#include <cstddef>

#define NB 4
#define NT 1024
#define NE 768
#define NH 12
#define NHS 64
#define NL 6
#define NFF 3072
#define NV 50257
#define NTOK (NB*NT)   // 4096

// ---------------- embedding ----------------
__global__ __launch_bounds__(256) void embed_kernel(
    const int* __restrict__ idx, const float* __restrict__ tok,
    const float* __restrict__ pos, float* __restrict__ x)
{
  int bt = blockIdx.x;
  int token = idx[bt];
  int t = bt & (NT - 1);
  const float* tr = tok + (size_t)token * NE;
  const float* pr = pos + (size_t)t * NE;
  float* xr = x + (size_t)bt * NE;
  for (int i = threadIdx.x; i < NE; i += 256)
    xr[i] = tr[i] + pr[i];
}

// ---------------- layernorm (row = 768) ----------------
__global__ __launch_bounds__(256) void ln_kernel(
    const float* __restrict__ in, const float* __restrict__ sc,
    const float* __restrict__ bi, float* __restrict__ out)
{
  int row = blockIdx.x, tid = threadIdx.x;
  const float* xr = in + (size_t)row * NE;
  float v0 = xr[tid], v1 = xr[tid + 256], v2 = xr[tid + 512];
  float s = v0 + v1 + v2;
  float ss = v0 * v0 + v1 * v1 + v2 * v2;
  #pragma unroll
  for (int o = 32; o > 0; o >>= 1) {
    s  += __shfl_xor(s, o);
    ss += __shfl_xor(ss, o);
  }
  __shared__ float r1[4], r2[4];
  if ((tid & 63) == 0) { r1[tid >> 6] = s; r2[tid >> 6] = ss; }
  __syncthreads();
  float tot = r1[0] + r1[1] + r1[2] + r1[3];
  float tss = r2[0] + r2[1] + r2[2] + r2[3];
  float mu  = tot * (1.f / NE);
  float var = tss * (1.f / NE) - mu * mu;
  float rs  = rsqrtf(var + 1e-5f);
  float* orow = out + (size_t)row * NE;
  orow[tid]       = (v0 - mu) * rs * sc[tid]       + bi[tid];
  orow[tid + 256] = (v1 - mu) * rs * sc[tid + 256] + bi[tid + 256];
  orow[tid + 512] = (v2 - mu) * rs * sc[tid + 512] + bi[tid + 512];
}

// ---------------- transpose Wq/Wk/Wv [H,E,HS] -> [E, H*HS] ----------------
__global__ __launch_bounds__(256) void tqkv_kernel(
    const float* __restrict__ W, float* __restrict__ WT)
{
  int n = blockIdx.x * 256 + threadIdx.x;
  if (n >= NE * NE) return;
  int e = n / NE, c = n - e * NE;
  int h = c >> 6, d = c & 63;
  WT[n] = W[((size_t)h * NE + e) * NHS + d];
}

// ---------------- generic f32 GEMM: C = [R +] A@B [+ bias] [relu] ----------------
// A[M,K], B[K,N], C[M,N] row-major. 64x64 tile, BK=16, 256 thr, 4x4/thread.
#define TBM 64
#define TBN 64
#define TBK 16
__global__ __launch_bounds__(256) void gemm_kernel(
    const float* __restrict__ A, const float* __restrict__ B,
    float* C, const float* __restrict__ bias, const float* R,
    int M, int N, int K, int relu)
{
  __shared__ float As[TBK][TBM + 4];  // k-major; +4 pad keeps 16B align + banks spread
  __shared__ float Bs[TBK][TBN];
  int tid = threadIdx.x;
  int tx = tid & 15, ty = tid >> 4;
  int row0 = blockIdx.y * TBM, col0 = blockIdx.x * TBN;
  float acc[4][4] = {};
  for (int k0 = 0; k0 < K; k0 += TBK) {
    #pragma unroll
    for (int i = 0; i < 4; ++i) {
      int idx = tid + i * 256;
      int r = idx >> 4, kk = idx & 15;
      As[kk][r] = A[(size_t)(row0 + r) * K + k0 + kk];
    }
    #pragma unroll
    for (int i = 0; i < 4; ++i) {
      int idx = tid + i * 256;
      int kk = idx >> 6, c = idx & 63;
      int col = col0 + c;
      Bs[kk][c] = (col < N) ? B[(size_t)(k0 + kk) * N + col] : 0.f;
    }
    __syncthreads();
    #pragma unroll
    for (int kk = 0; kk < TBK; ++kk) {
      float a[4], b[4];
      #pragma unroll
      for (int i = 0; i < 4; ++i) a[i] = As[kk][ty * 4 + i];
      #pragma unroll
      for (int j = 0; j < 4; ++j) b[j] = Bs[kk][tx * 4 + j];
      #pragma unroll
      for (int i = 0; i < 4; ++i)
        #pragma unroll
        for (int j = 0; j < 4; ++j)
          acc[i][j] += a[i] * b[j];
    }
    __syncthreads();
  }
  #pragma unroll
  for (int i = 0; i < 4; ++i) {
    int r = row0 + ty * 4 + i;
    if (r >= M) continue;
    #pragma unroll
    for (int j = 0; j < 4; ++j) {
      int c = col0 + tx * 4 + j;
      if (c >= N) continue;
      float v = acc[i][j];
      if (bias) v += bias[c];
      if (R)    v += R[(size_t)r * N + c];
      if (relu) v = fmaxf(v, 0.f);
      C[(size_t)r * N + c] = v;
    }
  }
}

// ---------------- causal attention ----------------
// Q,K,V,O: [NTOK, NE] (head h occupies cols h*64..h*64+63).
// grid: (T/8, H, B), block 256. Scores for 8 q-rows staged in LDS, 2-pass softmax.
#define QT 8
__global__ __launch_bounds__(256) void attn_kernel(
    const float* __restrict__ Q, const float* __restrict__ K,
    const float* __restrict__ V, float* __restrict__ O)
{
  __shared__ float scs[QT][NT];     // 32 KB
  __shared__ float qs[QT][64];
  __shared__ float ks[64][65];      // +1 pad: conflict-free scalar reads
  __shared__ float inv_s[QT];
  int qt = blockIdx.x, h = blockIdx.y, b = blockIdx.z;
  int tid = threadIdx.x;
  int rowbase = b * NT + qt * QT;
  int colbase = h * 64;
  for (int i = tid; i < QT * 64; i += 256) {
    int qi = i >> 6, d = i & 63;
    qs[qi][d] = Q[(size_t)(rowbase + qi) * NE + colbase + d];
  }
  int s_end = qt * QT + QT;   // causal: keys 0..s_end-1 cover max t in tile
  __syncthreads();
  for (int s0 = 0; s0 < s_end; s0 += 64) {
    for (int i = tid; i < 64 * 64; i += 256) {
      int si = i >> 6, d = i & 63;
      ks[si][d] = K[(size_t)(b * NT + s0 + si) * NE + colbase + d];
    }
    __syncthreads();
    for (int i = tid; i < QT * 64; i += 256) {
      int qi = i >> 6, sl = i & 63;
      float acc = 0.f;
      #pragma unroll
      for (int d = 0; d < 64; ++d) acc += qs[qi][d] * ks[sl][d];
      int s = s0 + sl;
      int t = qt * QT + qi;
      scs[qi][s] = (s <= t) ? acc * 0.125f : -1e30f;
    }
    __syncthreads();
  }
  // softmax: 32 lanes per row
  {
    int qi = tid >> 5, w = tid & 31;
    float m = -1e30f;
    for (int s = w; s < s_end; s += 32) m = fmaxf(m, scs[qi][s]);
    #pragma unroll
    for (int o = 16; o > 0; o >>= 1) m = fmaxf(m, __shfl_xor(m, o));
    float sum = 0.f;
    for (int s = w; s < s_end; s += 32) {
      float p = __expf(scs[qi][s] - m);
      scs[qi][s] = p;
      sum += p;
    }
    #pragma unroll
    for (int o = 16; o > 0; o >>= 1) sum += __shfl_xor(sum, o);
    if (w == 0) inv_s[qi] = 1.f / sum;
  }
  __syncthreads();
  // PV
  for (int i = tid; i < QT * 64; i += 256) {
    int qi = i >> 6, d = i & 63;
    float acc = 0.f;
    #pragma unroll 4
    for (int s = 0; s < s_end; ++s)
      acc += scs[qi][s] * V[(size_t)(b * NT + s) * NE + colbase + d];
    O[(size_t)(rowbase + qi) * NE + colbase + d] = acc * inv_s[qi];
  }
}

// ---------------- per-row NLL (online logsumexp over V) ----------------
__global__ __launch_bounds__(256) void nll_kernel(
    const float* __restrict__ logits, const int* __restrict__ targets,
    float* __restrict__ nll)
{
  int row = blockIdx.x, tid = threadIdx.x;
  const float* lr = logits + (size_t)row * NV;
  float m = -1e30f, s = 0.f;
  for (int v = tid; v < NV; v += 256) {
    float x = lr[v];
    if (x > m) { s = s * __expf(m - x) + 1.f; m = x; }
    else       { s += __expf(x - m); }
  }
  #pragma unroll
  for (int o = 32; o > 0; o >>= 1) {
    float m2 = __shfl_xor(m, o), s2 = __shfl_xor(s, o);
    float M = fmaxf(m, m2);
    s = s * __expf(m - M) + s2 * __expf(m2 - M);
    m = M;
  }
  __shared__ float ms[4], ss[4];
  if ((tid & 63) == 0) { ms[tid >> 6] = m; ss[tid >> 6] = s; }
  __syncthreads();
  if (tid == 0) {
    float M = fmaxf(fmaxf(ms[0], ms[1]), fmaxf(ms[2], ms[3]));
    float S = ss[0] * __expf(ms[0] - M) + ss[1] * __expf(ms[1] - M)
            + ss[2] * __expf(ms[2] - M) + ss[3] * __expf(ms[3] - M);
    float tgt = lr[targets[row]];
    nll[row] = -(tgt - M - logf(S));
  }
}

__global__ __launch_bounds__(256) void loss_kernel(
    const float* __restrict__ nll, float* __restrict__ out)
{
  int tid = threadIdx.x;
  float s = 0.f;
  for (int i = tid; i < NTOK; i += 256) s += nll[i];
  #pragma unroll
  for (int o = 32; o > 0; o >>= 1) s += __shfl_xor(s, o);
  __shared__ float red[4];
  if ((tid & 63) == 0) red[tid >> 6] = s;
  __syncthreads();
  if (tid == 0) out[0] = (red[0] + red[1] + red[2] + red[3]) * (1.f / NTOK);
}

// ---------------- host ----------------
static inline void gemm(const float* A, const float* B, float* C,
                        const float* bias, const float* R,
                        int M, int N, int K, int relu, hipStream_t st)
{
  dim3 g((N + TBN - 1) / TBN, (M + TBM - 1) / TBM);
  gemm_kernel<<<g, dim3(256), 0, st>>>(A, B, C, bias, R, M, N, K, relu);
}

extern "C" void kernel_launch(void* const* d_in, const int* in_sizes, int n_in,
                              void* d_out, int out_size, void* d_ws, size_t ws_size,
                              hipStream_t stream)
{
  const int*   idx     = (const int*)  d_in[0];
  const int*   targets = (const int*)  d_in[1];
  const float* tok_emb = (const float*)d_in[2];
  const float* pos_emb = (const float*)d_in[3];
  const float* Wq      = (const float*)d_in[4];
  const float* Wk      = (const float*)d_in[5];
  const float* Wv      = (const float*)d_in[6];
  const float* Wo      = (const float*)d_in[7];
  const float* bo      = (const float*)d_in[8];
  const float* ln1_s   = (const float*)d_in[9];
  const float* ln1_b   = (const float*)d_in[10];
  const float* ln2_s   = (const float*)d_in[11];
  const float* ln2_b   = (const float*)d_in[12];
  const float* W1      = (const float*)d_in[13];
  const float* b1      = (const float*)d_in[14];
  const float* W2      = (const float*)d_in[15];
  const float* b2      = (const float*)d_in[16];
  const float* lnf_s   = (const float*)d_in[17];
  const float* lnf_b   = (const float*)d_in[18];
  const float* Wlm     = (const float*)d_in[19];
  const float* blm     = (const float*)d_in[20];
  float* out = (float*)d_out;

  const size_t XE = (size_t)NTOK * NE;      // 3,145,728
  float* ws  = (float*)d_ws;
  float* x   = ws;
  float* h   = x   + XE;
  float* q   = h   + XE;
  float* k   = q   + XE;
  float* v   = k   + XE;
  float* att = v   + XE;
  float* f   = att + XE;                    // [NTOK, NFF]
  float* wTq = f   + (size_t)NTOK * NFF;
  float* wTk = wTq + (size_t)NE * NE;
  float* wTv = wTk + (size_t)NE * NE;
  float* nll = wTv + (size_t)NE * NE;       // NTOK floats

  embed_kernel<<<dim3(NTOK), dim3(256), 0, stream>>>(idx, tok_emb, pos_emb, x);

  const int tq_blocks = (NE * NE + 255) / 256;
  for (int l = 0; l < NL; ++l) {
    const float* wq_l = Wq + (size_t)l * NH * NE * NHS;
    const float* wk_l = Wk + (size_t)l * NH * NE * NHS;
    const float* wv_l = Wv + (size_t)l * NH * NE * NHS;
    const float* wo_l = Wo + (size_t)l * NE * NE;
    const float* w1_l = W1 + (size_t)l * NE * NFF;
    const float* w2_l = W2 + (size_t)l * NFF * NE;

    ln_kernel<<<dim3(NTOK), dim3(256), 0, stream>>>(x, ln1_s + l*NE, ln1_b + l*NE, h);

    tqkv_kernel<<<dim3(tq_blocks), dim3(256), 0, stream>>>(wq_l, wTq);
    tqkv_kernel<<<dim3(tq_blocks), dim3(256), 0, stream>>>(wk_l, wTk);
    tqkv_kernel<<<dim3(tq_blocks), dim3(256), 0, stream>>>(wv_l, wTv);

    gemm(h, wTq, q, nullptr, nullptr, NTOK, NE, NE, 0, stream);
    gemm(h, wTk, k, nullptr, nullptr, NTOK, NE, NE, 0, stream);
    gemm(h, wTv, v, nullptr, nullptr, NTOK, NE, NE, 0, stream);

    attn_kernel<<<dim3(NT / QT, NH, NB), dim3(256), 0, stream>>>(q, k, v, att);

    // x = x + att @ Wo + bo
    gemm(att, wo_l, x, bo + l*NE, x, NTOK, NE, NE, 0, stream);

    ln_kernel<<<dim3(NTOK), dim3(256), 0, stream>>>(x, ln2_s + l*NE, ln2_b + l*NE, h);

    // f = relu(h @ W1 + b1)
    gemm(h, w1_l, f, b1 + l*NFF, nullptr, NTOK, NFF, NE, 1, stream);
    // x = x + f @ W2 + b2
    gemm(f, w2_l, x, b2 + l*NE, x, NTOK, NE, NFF, 0, stream);
  }

  ln_kernel<<<dim3(NTOK), dim3(256), 0, stream>>>(x, lnf_s, lnf_b, h);
  // logits -> d_out
  gemm(h, Wlm, out, blm, nullptr, NTOK, NV, NE, 0, stream);

  nll_kernel<<<dim3(NTOK), dim3(256), 0, stream>>>(out, targets, nll);
  loss_kernel<<<dim3(1), dim3(256), 0, stream>>>(nll, out + (size_t)NTOK * NV);
}

// Round 2
// 6394.267 us; speedup vs baseline: 2.3052x; 2.3052x over previous
//
#include <hip/hip_runtime.h>
#include <hip/hip_bf16.h>
#include <cstdint>
#include <cstddef>

#define NB 4
#define NT 1024
#define NE 768
#define NH 12
#define NHS 64
#define NL 6
#define NFF 3072
#define NV 50257
#define NVP 50304          // 50257 padded to /128
#define NTOK (NB*NT)       // 4096

typedef __attribute__((ext_vector_type(8))) short short8;
typedef __attribute__((ext_vector_type(4))) float f32x4;

// ---------------- embedding ----------------
__global__ __launch_bounds__(256) void embed_kernel(
    const int* __restrict__ idx, const float* __restrict__ tok,
    const float* __restrict__ pos, float* __restrict__ x)
{
  int bt = blockIdx.x;
  int token = idx[bt];
  int t = bt & (NT - 1);
  const float* tr = tok + (size_t)token * NE;
  const float* pr = pos + (size_t)t * NE;
  float* xr = x + (size_t)bt * NE;
  for (int i = threadIdx.x; i < NE; i += 256)
    xr[i] = tr[i] + pr[i];
}

// ---------------- layernorm (row = 768), bf16 out ----------------
__global__ __launch_bounds__(256) void ln_kernel(
    const float* __restrict__ in, const float* __restrict__ sc,
    const float* __restrict__ bi, __hip_bfloat16* __restrict__ out)
{
  int row = blockIdx.x, tid = threadIdx.x;
  const float* xr = in + (size_t)row * NE;
  float v0 = xr[tid], v1 = xr[tid + 256], v2 = xr[tid + 512];
  float s = v0 + v1 + v2;
  float ss = v0 * v0 + v1 * v1 + v2 * v2;
  #pragma unroll
  for (int o = 32; o > 0; o >>= 1) {
    s  += __shfl_xor(s, o);
    ss += __shfl_xor(ss, o);
  }
  __shared__ float r1[4], r2[4];
  if ((tid & 63) == 0) { r1[tid >> 6] = s; r2[tid >> 6] = ss; }
  __syncthreads();
  float tot = r1[0] + r1[1] + r1[2] + r1[3];
  float tss = r2[0] + r2[1] + r2[2] + r2[3];
  float mu  = tot * (1.f / NE);
  float var = tss * (1.f / NE) - mu * mu;
  float rs  = rsqrtf(var + 1e-5f);
  __hip_bfloat16* orow = out + (size_t)row * NE;
  orow[tid]       = __float2bfloat16((v0 - mu) * rs * sc[tid]       + bi[tid]);
  orow[tid + 256] = __float2bfloat16((v1 - mu) * rs * sc[tid + 256] + bi[tid + 256]);
  orow[tid + 512] = __float2bfloat16((v2 - mu) * rs * sc[tid + 512] + bi[tid + 512]);
}

// ------- transpose+convert: src f32 [R][Cs] (per z) -> dst bf16 [Cd][R] -------
// pad rows c in [Cs,Cd) are zero-filled. grid: (Cd/32, R/32, Z)
__global__ __launch_bounds__(256) void tconv_kernel(
    const float* __restrict__ src, __hip_bfloat16* __restrict__ dst,
    int R, int Cs, int Cd)
{
  __shared__ float t[32][33];
  int z = blockIdx.z;
  src += (size_t)z * R * Cs;
  dst += (size_t)z * Cd * R;
  int c0 = blockIdx.x * 32, r0 = blockIdx.y * 32;
  int tx = threadIdx.x & 31, ty = threadIdx.x >> 5;   // ty 0..7
  #pragma unroll
  for (int i = 0; i < 32; i += 8) {
    int r = r0 + ty + i, c = c0 + tx;
    t[ty + i][tx] = (c < Cs) ? src[(size_t)r * Cs + c] : 0.f;
  }
  __syncthreads();
  #pragma unroll
  for (int i = 0; i < 32; i += 8) {
    int c = c0 + ty + i, r = r0 + tx;
    if (c < Cd) dst[(size_t)c * R + r] = __float2bfloat16(t[tx][ty + i]);
  }
}

// ---------------- bf16 MFMA GEMM (m97 structure) ----------------
// A [M][K] bf16 (lda=K), BT [Npad][K] bf16 (B^T, ldb=K), C row-major [M][N].
// 128x128 tile, BK=64, 256 thr (4 waves, 2x2), each wave 64x64 = 4x4 frags 16x16x32.
#define BM 128
#define BN 128
__global__ __launch_bounds__(256) void gemm_bf(
    const __hip_bfloat16* __restrict__ A,
    const __hip_bfloat16* __restrict__ BT,
    float* __restrict__ Cf, __hip_bfloat16* __restrict__ Cbf,
    const float* __restrict__ bias, const float* __restrict__ Rres,
    int M, int N, int K, int relu)
{
  __shared__ __hip_bfloat16 As[BM][64];
  __shared__ __hip_bfloat16 Bs[BN][64];
  int tid = threadIdx.x;
  int lane = tid & 63;
  int w = __builtin_amdgcn_readfirstlane(tid >> 6);
  int wr = w >> 1, wc = w & 1;
  int row0 = blockIdx.y * BM;
  int col0 = blockIdx.x * BN;

  f32x4 acc[4][4] = {};

  for (int k0 = 0; k0 < K; k0 += 64) {
    // stage A,B tiles: 16 KB each, global_load_lds width=16, linear LDS order
    #pragma unroll
    for (int r = 0; r < 4; ++r) {
      int c = r * 256 + w * 64 + lane;
      int trow = c >> 3, tcol = (c & 7) << 3;
      const __hip_bfloat16* ga = A  + (size_t)(row0 + trow) * K + k0 + tcol;
      const __hip_bfloat16* gb = BT + (size_t)(col0 + trow) * K + k0 + tcol;
      unsigned lofs = (unsigned)(r * 256 + w * 64) * 16;
      __builtin_amdgcn_global_load_lds(
          (const __attribute__((address_space(1))) void*)ga,
          (__attribute__((address_space(3))) void*)((char*)&As[0][0] + lofs),
          16, 0, 0);
      __builtin_amdgcn_global_load_lds(
          (const __attribute__((address_space(1))) void*)gb,
          (__attribute__((address_space(3))) void*)((char*)&Bs[0][0] + lofs),
          16, 0, 0);
    }
    __syncthreads();
    int g8 = (lane >> 4) << 3;
    #pragma unroll
    for (int kk = 0; kk < 64; kk += 32) {
      short8 a[4], b[4];
      #pragma unroll
      for (int m = 0; m < 4; ++m)
        a[m] = *(const short8*)&As[wr * 64 + m * 16 + (lane & 15)][kk + g8];
      #pragma unroll
      for (int n = 0; n < 4; ++n)
        b[n] = *(const short8*)&Bs[wc * 64 + n * 16 + (lane & 15)][kk + g8];
      #pragma unroll
      for (int m = 0; m < 4; ++m)
        #pragma unroll
        for (int n = 0; n < 4; ++n)
          acc[m][n] = __builtin_amdgcn_mfma_f32_16x16x32_bf16(a[m], b[n], acc[m][n], 0, 0, 0);
    }
    __syncthreads();
  }

  int cr = lane >> 4;       // C/D: row = cr*4+e, col = lane&15 (m89-verified)
  int cc = lane & 15;
  #pragma unroll
  for (int m = 0; m < 4; ++m) {
    #pragma unroll
    for (int n = 0; n < 4; ++n) {
      int col = col0 + wc * 64 + n * 16 + cc;
      if (col >= N) continue;
      float bv = bias ? bias[col] : 0.f;
      #pragma unroll
      for (int e = 0; e < 4; ++e) {
        int row = row0 + wr * 64 + m * 16 + cr * 4 + e;
        float v = acc[m][n][e] + bv;
        size_t off = (size_t)row * N + col;
        if (Rres) v += Rres[off];
        if (relu) v = fmaxf(v, 0.f);
        if (Cf)  Cf[off] = v;
        if (Cbf) Cbf[off] = __float2bfloat16(v);
      }
    }
  }
}

// ---------------- causal attention (bf16 in/out, f32 math) ----------------
#define QT 8
__global__ __launch_bounds__(256) void attn_kernel(
    const __hip_bfloat16* __restrict__ Q, const __hip_bfloat16* __restrict__ K,
    const __hip_bfloat16* __restrict__ V, __hip_bfloat16* __restrict__ O)
{
  __shared__ float scs[QT][NT];     // 32 KB
  __shared__ float qs[QT][64];
  __shared__ float ks[64][65];
  __shared__ float inv_s[QT];
  int qt = blockIdx.x, h = blockIdx.y, b = blockIdx.z;
  int tid = threadIdx.x;
  int rowbase = b * NT + qt * QT;
  int colbase = h * 64;
  for (int i = tid; i < QT * 64; i += 256) {
    int qi = i >> 6, d = i & 63;
    qs[qi][d] = __bfloat162float(Q[(size_t)(rowbase + qi) * NE + colbase + d]);
  }
  int s_end = qt * QT + QT;
  __syncthreads();
  for (int s0 = 0; s0 < s_end; s0 += 64) {
    for (int i = tid; i < 64 * 64; i += 256) {
      int si = i >> 6, d = i & 63;
      ks[si][d] = __bfloat162float(K[(size_t)(b * NT + s0 + si) * NE + colbase + d]);
    }
    __syncthreads();
    for (int i = tid; i < QT * 64; i += 256) {
      int qi = i >> 6, sl = i & 63;
      float acc = 0.f;
      #pragma unroll
      for (int d = 0; d < 64; ++d) acc += qs[qi][d] * ks[sl][d];
      int s = s0 + sl;
      int t = qt * QT + qi;
      scs[qi][s] = (s <= t) ? acc * 0.125f : -1e30f;
    }
    __syncthreads();
  }
  {
    int qi = tid >> 5, wv = tid & 31;
    float m = -1e30f;
    for (int s = wv; s < s_end; s += 32) m = fmaxf(m, scs[qi][s]);
    #pragma unroll
    for (int o = 16; o > 0; o >>= 1) m = fmaxf(m, __shfl_xor(m, o));
    float sum = 0.f;
    for (int s = wv; s < s_end; s += 32) {
      float p = __expf(scs[qi][s] - m);
      scs[qi][s] = p;
      sum += p;
    }
    #pragma unroll
    for (int o = 16; o > 0; o >>= 1) sum += __shfl_xor(sum, o);
    if (wv == 0) inv_s[qi] = 1.f / sum;
  }
  __syncthreads();
  for (int i = tid; i < QT * 64; i += 256) {
    int qi = i >> 6, d = i & 63;
    float acc = 0.f;
    #pragma unroll 4
    for (int s = 0; s < s_end; ++s)
      acc += scs[qi][s] * __bfloat162float(V[(size_t)(b * NT + s) * NE + colbase + d]);
    O[(size_t)(rowbase + qi) * NE + colbase + d] = __float2bfloat16(acc * inv_s[qi]);
  }
}

// ---------------- per-row NLL ----------------
__global__ __launch_bounds__(256) void nll_kernel(
    const float* __restrict__ logits, const int* __restrict__ targets,
    float* __restrict__ nll)
{
  int row = blockIdx.x, tid = threadIdx.x;
  const float* lr = logits + (size_t)row * NV;
  float m = -1e30f, s = 0.f;
  for (int v = tid; v < NV; v += 256) {
    float x = lr[v];
    if (x > m) { s = s * __expf(m - x) + 1.f; m = x; }
    else       { s += __expf(x - m); }
  }
  #pragma unroll
  for (int o = 32; o > 0; o >>= 1) {
    float m2 = __shfl_xor(m, o), s2 = __shfl_xor(s, o);
    float M = fmaxf(m, m2);
    s = s * __expf(m - M) + s2 * __expf(m2 - M);
    m = M;
  }
  __shared__ float ms[4], ss[4];
  if ((tid & 63) == 0) { ms[tid >> 6] = m; ss[tid >> 6] = s; }
  __syncthreads();
  if (tid == 0) {
    float M = fmaxf(fmaxf(ms[0], ms[1]), fmaxf(ms[2], ms[3]));
    float S = ss[0] * __expf(ms[0] - M) + ss[1] * __expf(ms[1] - M)
            + ss[2] * __expf(ms[2] - M) + ss[3] * __expf(ms[3] - M);
    float tgt = lr[targets[row]];
    nll[row] = -(tgt - M - logf(S));
  }
}

__global__ __launch_bounds__(256) void loss_kernel(
    const float* __restrict__ nll, float* __restrict__ out)
{
  int tid = threadIdx.x;
  float s = 0.f;
  for (int i = tid; i < NTOK; i += 256) s += nll[i];
  #pragma unroll
  for (int o = 32; o > 0; o >>= 1) s += __shfl_xor(s, o);
  __shared__ float red[4];
  if ((tid & 63) == 0) red[tid >> 6] = s;
  __syncthreads();
  if (tid == 0) out[0] = (red[0] + red[1] + red[2] + red[3]) * (1.f / NTOK);
}

// ---------------- host ----------------
static inline void gemm(const __hip_bfloat16* A, const __hip_bfloat16* BT,
                        float* Cf, __hip_bfloat16* Cbf,
                        const float* bias, const float* Rres,
                        int M, int N, int Npad, int K, int relu, hipStream_t st)
{
  dim3 g(Npad / BN, M / BM);
  gemm_bf<<<g, dim3(256), 0, st>>>(A, BT, Cf, Cbf, bias, Rres, M, N, K, relu);
}

extern "C" void kernel_launch(void* const* d_in, const int* in_sizes, int n_in,
                              void* d_out, int out_size, void* d_ws, size_t ws_size,
                              hipStream_t stream)
{
  const int*   idx     = (const int*)  d_in[0];
  const int*   targets = (const int*)  d_in[1];
  const float* tok_emb = (const float*)d_in[2];
  const float* pos_emb = (const float*)d_in[3];
  const float* Wq      = (const float*)d_in[4];
  const float* Wk      = (const float*)d_in[5];
  const float* Wv      = (const float*)d_in[6];
  const float* Wo      = (const float*)d_in[7];
  const float* bo      = (const float*)d_in[8];
  const float* ln1_s   = (const float*)d_in[9];
  const float* ln1_b   = (const float*)d_in[10];
  const float* ln2_s   = (const float*)d_in[11];
  const float* ln2_b   = (const float*)d_in[12];
  const float* W1      = (const float*)d_in[13];
  const float* b1      = (const float*)d_in[14];
  const float* W2      = (const float*)d_in[15];
  const float* b2      = (const float*)d_in[16];
  const float* lnf_s   = (const float*)d_in[17];
  const float* lnf_b   = (const float*)d_in[18];
  const float* Wlm     = (const float*)d_in[19];
  const float* blm     = (const float*)d_in[20];
  float* out = (float*)d_out;

  typedef __hip_bfloat16 bf16;
  const size_t XE = (size_t)NTOK * NE;
  char* p = (char*)d_ws;
  float* x    = (float*)p;          p += XE * 4;
  bf16* h_bf  = (bf16*)p;           p += XE * 2;
  bf16* q_bf  = (bf16*)p;           p += XE * 2;
  bf16* k_bf  = (bf16*)p;           p += XE * 2;
  bf16* v_bf  = (bf16*)p;           p += XE * 2;
  bf16* att_bf= (bf16*)p;           p += XE * 2;
  bf16* f_bf  = (bf16*)p;           p += (size_t)NTOK * NFF * 2;
  bf16* wtq   = (bf16*)p;           p += (size_t)NE * NE * 2;
  bf16* wtk   = (bf16*)p;           p += (size_t)NE * NE * 2;
  bf16* wtv   = (bf16*)p;           p += (size_t)NE * NE * 2;
  bf16* wto   = (bf16*)p;           p += (size_t)NE * NE * 2;
  bf16* wt1   = (bf16*)p;           p += (size_t)NFF * NE * 2;
  bf16* wt2   = (bf16*)p;           p += (size_t)NE * NFF * 2;
  bf16* wtlm  = (bf16*)p;           p += (size_t)NVP * NE * 2;
  float* nll  = (float*)p;          p += (size_t)NTOK * 4;

  embed_kernel<<<dim3(NTOK), dim3(256), 0, stream>>>(idx, tok_emb, pos_emb, x);

  for (int l = 0; l < NL; ++l) {
    const float* wq_l = Wq + (size_t)l * NH * NE * NHS;
    const float* wk_l = Wk + (size_t)l * NH * NE * NHS;
    const float* wv_l = Wv + (size_t)l * NH * NE * NHS;
    const float* wo_l = Wo + (size_t)l * NE * NE;
    const float* w1_l = W1 + (size_t)l * NE * NFF;
    const float* w2_l = W2 + (size_t)l * NFF * NE;

    ln_kernel<<<dim3(NTOK), dim3(256), 0, stream>>>(x, ln1_s + l*NE, ln1_b + l*NE, h_bf);

    // weights -> bf16 [N][K]
    tconv_kernel<<<dim3(2, 24, NH), dim3(256), 0, stream>>>(wq_l, wtq, NE, NHS, NHS);
    tconv_kernel<<<dim3(2, 24, NH), dim3(256), 0, stream>>>(wk_l, wtk, NE, NHS, NHS);
    tconv_kernel<<<dim3(2, 24, NH), dim3(256), 0, stream>>>(wv_l, wtv, NE, NHS, NHS);
    tconv_kernel<<<dim3(24, 24, 1), dim3(256), 0, stream>>>(wo_l, wto, NE, NE, NE);
    tconv_kernel<<<dim3(96, 24, 1), dim3(256), 0, stream>>>(w1_l, wt1, NE, NFF, NFF);
    tconv_kernel<<<dim3(24, 96, 1), dim3(256), 0, stream>>>(w2_l, wt2, NFF, NE, NE);

    gemm(h_bf, wtq, nullptr, q_bf, nullptr, nullptr, NTOK, NE, NE, NE, 0, stream);
    gemm(h_bf, wtk, nullptr, k_bf, nullptr, nullptr, NTOK, NE, NE, NE, 0, stream);
    gemm(h_bf, wtv, nullptr, v_bf, nullptr, nullptr, NTOK, NE, NE, NE, 0, stream);

    attn_kernel<<<dim3(NT / QT, NH, NB), dim3(256), 0, stream>>>(q_bf, k_bf, v_bf, att_bf);

    // x = x + att @ Wo + bo
    gemm(att_bf, wto, x, nullptr, bo + l*NE, x, NTOK, NE, NE, NE, 0, stream);

    ln_kernel<<<dim3(NTOK), dim3(256), 0, stream>>>(x, ln2_s + l*NE, ln2_b + l*NE, h_bf);

    // f = relu(h @ W1 + b1)  (bf16 out only)
    gemm(h_bf, wt1, nullptr, f_bf, b1 + l*NFF, nullptr, NTOK, NFF, NFF, NE, 1, stream);
    // x = x + f @ W2 + b2
    gemm(f_bf, wt2, x, nullptr, b2 + l*NE, x, NTOK, NE, NE, NFF, 0, stream);
  }

  ln_kernel<<<dim3(NTOK), dim3(256), 0, stream>>>(x, lnf_s, lnf_b, h_bf);
  tconv_kernel<<<dim3(NVP/32, 24, 1), dim3(256), 0, stream>>>(Wlm, wtlm, NE, NV, NVP);
  gemm(h_bf, wtlm, out, nullptr, blm, nullptr, NTOK, NV, NVP, NE, 0, stream);

  nll_kernel<<<dim3(NTOK), dim3(256), 0, stream>>>(out, targets, nll);
  loss_kernel<<<dim3(1), dim3(256), 0, stream>>>(nll, out + (size_t)NTOK * NV);
}

// Round 3
// 2875.301 us; speedup vs baseline: 5.1263x; 2.2239x over previous
//
#include <hip/hip_runtime.h>
#include <hip/hip_bf16.h>
#include <cstdint>
#include <cstddef>

#define NB 4
#define NT 1024
#define NE 768
#define NH 12
#define NHS 64
#define NL 6
#define NFF 3072
#define NV 50257
#define NVP 50304          // 50257 padded to /128
#define NTOK (NB*NT)       // 4096

typedef __attribute__((ext_vector_type(8))) short short8;
typedef __attribute__((ext_vector_type(4))) float f32x4;
typedef __hip_bfloat16 bf16;

// ---------------- embedding ----------------
__global__ __launch_bounds__(256) void embed_kernel(
    const int* __restrict__ idx, const float* __restrict__ tok,
    const float* __restrict__ pos, float* __restrict__ x)
{
  int bt = blockIdx.x;
  int token = idx[bt];
  int t = bt & (NT - 1);
  const float* tr = tok + (size_t)token * NE;
  const float* pr = pos + (size_t)t * NE;
  float* xr = x + (size_t)bt * NE;
  for (int i = threadIdx.x; i < NE; i += 256)
    xr[i] = tr[i] + pr[i];
}

// ---------------- layernorm (row = 768), bf16 out ----------------
__global__ __launch_bounds__(256) void ln_kernel(
    const float* __restrict__ in, const float* __restrict__ sc,
    const float* __restrict__ bi, bf16* __restrict__ out)
{
  int row = blockIdx.x, tid = threadIdx.x;
  const float* xr = in + (size_t)row * NE;
  float v0 = xr[tid], v1 = xr[tid + 256], v2 = xr[tid + 512];
  float s = v0 + v1 + v2;
  float ss = v0 * v0 + v1 * v1 + v2 * v2;
  #pragma unroll
  for (int o = 32; o > 0; o >>= 1) {
    s  += __shfl_xor(s, o);
    ss += __shfl_xor(ss, o);
  }
  __shared__ float r1[4], r2[4];
  if ((tid & 63) == 0) { r1[tid >> 6] = s; r2[tid >> 6] = ss; }
  __syncthreads();
  float tot = r1[0] + r1[1] + r1[2] + r1[3];
  float tss = r2[0] + r2[1] + r2[2] + r2[3];
  float mu  = tot * (1.f / NE);
  float var = tss * (1.f / NE) - mu * mu;
  float rs  = rsqrtf(var + 1e-5f);
  bf16* orow = out + (size_t)row * NE;
  orow[tid]       = __float2bfloat16((v0 - mu) * rs * sc[tid]       + bi[tid]);
  orow[tid + 256] = __float2bfloat16((v1 - mu) * rs * sc[tid + 256] + bi[tid + 256]);
  orow[tid + 512] = __float2bfloat16((v2 - mu) * rs * sc[tid + 512] + bi[tid + 512]);
}

// ------- transpose+convert: src f32 [R][Cs] (per z) -> dst bf16 [Cd][R] -------
__global__ __launch_bounds__(256) void tconv_kernel(
    const float* __restrict__ src, bf16* __restrict__ dst,
    int R, int Cs, int Cd)
{
  __shared__ float t[32][33];
  int z = blockIdx.z;
  src += (size_t)z * R * Cs;
  dst += (size_t)z * Cd * R;
  int c0 = blockIdx.x * 32, r0 = blockIdx.y * 32;
  int tx = threadIdx.x & 31, ty = threadIdx.x >> 5;
  #pragma unroll
  for (int i = 0; i < 32; i += 8) {
    int r = r0 + ty + i, c = c0 + tx;
    t[ty + i][tx] = (c < Cs) ? src[(size_t)r * Cs + c] : 0.f;
  }
  __syncthreads();
  #pragma unroll
  for (int i = 0; i < 32; i += 8) {
    int c = c0 + ty + i, r = r0 + tx;
    if (c < Cd) dst[(size_t)c * R + r] = __float2bfloat16(t[tx][ty + i]);
  }
}

// ---------------- bf16 MFMA GEMM (m97 structure) ----------------
#define BM 128
#define BN 128
__global__ __launch_bounds__(256) void gemm_bf(
    const bf16* __restrict__ A,
    const bf16* __restrict__ BT,
    float* __restrict__ Cf, bf16* __restrict__ Cbf,
    const float* __restrict__ bias, const float* __restrict__ Rres,
    int M, int N, int K, int relu)
{
  __shared__ bf16 As[BM][64];
  __shared__ bf16 Bs[BN][64];
  int tid = threadIdx.x;
  int lane = tid & 63;
  int w = __builtin_amdgcn_readfirstlane(tid >> 6);
  int wr = w >> 1, wc = w & 1;
  int row0 = blockIdx.y * BM;
  int col0 = blockIdx.x * BN;

  f32x4 acc[4][4] = {};

  for (int k0 = 0; k0 < K; k0 += 64) {
    #pragma unroll
    for (int r = 0; r < 4; ++r) {
      int c = r * 256 + w * 64 + lane;
      int trow = c >> 3, tcol = (c & 7) << 3;
      const bf16* ga = A  + (size_t)(row0 + trow) * K + k0 + tcol;
      const bf16* gb = BT + (size_t)(col0 + trow) * K + k0 + tcol;
      unsigned lofs = (unsigned)(r * 256 + w * 64) * 16;
      __builtin_amdgcn_global_load_lds(
          (const __attribute__((address_space(1))) void*)ga,
          (__attribute__((address_space(3))) void*)((char*)&As[0][0] + lofs),
          16, 0, 0);
      __builtin_amdgcn_global_load_lds(
          (const __attribute__((address_space(1))) void*)gb,
          (__attribute__((address_space(3))) void*)((char*)&Bs[0][0] + lofs),
          16, 0, 0);
    }
    __syncthreads();
    int g8 = (lane >> 4) << 3;
    #pragma unroll
    for (int kk = 0; kk < 64; kk += 32) {
      short8 a[4], b[4];
      #pragma unroll
      for (int m = 0; m < 4; ++m)
        a[m] = *(const short8*)&As[wr * 64 + m * 16 + (lane & 15)][kk + g8];
      #pragma unroll
      for (int n = 0; n < 4; ++n)
        b[n] = *(const short8*)&Bs[wc * 64 + n * 16 + (lane & 15)][kk + g8];
      #pragma unroll
      for (int m = 0; m < 4; ++m)
        #pragma unroll
        for (int n = 0; n < 4; ++n)
          acc[m][n] = __builtin_amdgcn_mfma_f32_16x16x32_bf16(a[m], b[n], acc[m][n], 0, 0, 0);
    }
    __syncthreads();
  }

  int cr = lane >> 4;
  int cc = lane & 15;
  #pragma unroll
  for (int m = 0; m < 4; ++m) {
    #pragma unroll
    for (int n = 0; n < 4; ++n) {
      int col = col0 + wc * 64 + n * 16 + cc;
      if (col >= N) continue;
      float bv = bias ? bias[col] : 0.f;
      #pragma unroll
      for (int e = 0; e < 4; ++e) {
        int row = row0 + wr * 64 + m * 16 + cr * 4 + e;
        float v = acc[m][n][e] + bv;
        size_t off = (size_t)row * N + col;
        if (Rres) v += Rres[off];
        if (relu) v = fmaxf(v, 0.f);
        if (Cf)  Cf[off] = v;
        if (Cbf) Cbf[off] = __float2bfloat16(v);
      }
    }
  }
}

// ---------------- flash attention, MFMA, online softmax ----------------
// grid (T/64, H, B), 256 thr = 4 waves x 16 q-rows. KBLK=64.
// Swapped QK^T: S^T[s][q] = mfma(K_frag, Q_frag) -> col q = lane&15 (lane-local row softmax).
static __device__ inline unsigned short bfbits(float x) {
  bf16 h = __float2bfloat16(x);
  return *reinterpret_cast<unsigned short*>(&h);
}

__global__ __launch_bounds__(256) void fattn_kernel(
    const bf16* __restrict__ Q, const bf16* __restrict__ K,
    const bf16* __restrict__ V, bf16* __restrict__ O)
{
  __shared__ unsigned short Ks[64][72];      // K[s][d], pad->144B stride
  __shared__ unsigned short Vt[64][72];      // V^T[d][s]
  __shared__ unsigned short Pl[4][16][72];   // per-wave P[q][s]
  int qt = blockIdx.x, h = blockIdx.y, b = blockIdx.z;
  int tid = threadIdx.x;
  int lane = tid & 63;
  int w = tid >> 6;
  int l15 = lane & 15, g = lane >> 4;
  int brow = b * NT;
  int qbase = qt * 64;
  int q_loc = w * 16 + l15;

  // Q fragments (held in regs for the whole block)
  short8 bq[2];
  {
    const bf16* qp = Q + (size_t)(brow + qbase + q_loc) * NE + h * 64 + g * 8;
    bq[0] = *(const short8*)qp;
    bq[1] = *(const short8*)(qp + 32);
  }

  float m_run = -1e30f, l_run = 0.f;
  f32x4 acc[4] = {};   // O^T: row d = dm*16+g*4+e, col q = l15

  for (int kt = 0; kt <= qt; ++kt) {
    int s0 = kt * 64;
    // stage K[s][d] and V^T[d][s]
    #pragma unroll
    for (int i = 0; i < 2; ++i) {
      int c = tid + i * 256;
      int row = c >> 3, colg = (c & 7) * 8;
      const bf16* kp = K + (size_t)(brow + s0 + row) * NE + h * 64 + colg;
      const bf16* vp = V + (size_t)(brow + s0 + row) * NE + h * 64 + colg;
      short8 kv = *(const short8*)kp;
      short8 vv = *(const short8*)vp;
      *(short8*)&Ks[row][colg] = kv;
      #pragma unroll
      for (int j = 0; j < 8; ++j)
        Vt[colg + j][row] = (unsigned short)vv[j];
    }
    __syncthreads();

    // S^T = K . Q^T  (16 scores per lane for q-col = l15)
    f32x4 sf[4] = {};
    #pragma unroll
    for (int kk = 0; kk < 2; ++kk) {
      #pragma unroll
      for (int m = 0; m < 4; ++m) {
        short8 a = *(const short8*)&Ks[m * 16 + l15][kk * 32 + g * 8];
        sf[m] = __builtin_amdgcn_mfma_f32_16x16x32_bf16(a, bq[kk], sf[m], 0, 0, 0);
      }
    }

    // scale + causal mask + online softmax
    float sv[4][4];
    float mx = -1e30f;
    bool diag = (kt == qt);
    #pragma unroll
    for (int m = 0; m < 4; ++m)
      #pragma unroll
      for (int e = 0; e < 4; ++e) {
        float v = sf[m][e] * 0.125f;
        if (diag) {
          int sl = m * 16 + g * 4 + e;
          if (sl > q_loc) v = -1e30f;
        }
        sv[m][e] = v;
        mx = fmaxf(mx, v);
      }
    mx = fmaxf(mx, __shfl_xor(mx, 16));
    mx = fmaxf(mx, __shfl_xor(mx, 32));
    float m_new = fmaxf(m_run, mx);
    float p[4][4];
    float rs = 0.f;
    #pragma unroll
    for (int m = 0; m < 4; ++m)
      #pragma unroll
      for (int e = 0; e < 4; ++e) {
        float pe = __expf(sv[m][e] - m_new);
        p[m][e] = pe;
        rs += pe;
      }
    rs += __shfl_xor(rs, 16);
    rs += __shfl_xor(rs, 32);
    float sc_old = __expf(m_run - m_new);
    l_run = l_run * sc_old + rs;
    m_run = m_new;
    #pragma unroll
    for (int dm = 0; dm < 4; ++dm)
      #pragma unroll
      for (int e = 0; e < 4; ++e)
        acc[dm][e] *= sc_old;

    // P -> LDS (wave-local; packed bf16 pairs)
    #pragma unroll
    for (int m = 0; m < 4; ++m)
      #pragma unroll
      for (int ep = 0; ep < 2; ++ep) {
        unsigned u = (unsigned)bfbits(p[m][2 * ep]) |
                     ((unsigned)bfbits(p[m][2 * ep + 1]) << 16);
        *(unsigned*)&Pl[w][l15][m * 16 + g * 4 + ep * 2] = u;
      }

    // O^T += V^T . P  (A row d = l15-based, B row q = l15)
    #pragma unroll
    for (int ks = 0; ks < 2; ++ks) {
      short8 pb = *(const short8*)&Pl[w][l15][ks * 32 + g * 8];
      #pragma unroll
      for (int dm = 0; dm < 4; ++dm) {
        short8 av = *(const short8*)&Vt[dm * 16 + l15][ks * 32 + g * 8];
        acc[dm] = __builtin_amdgcn_mfma_f32_16x16x32_bf16(av, pb, acc[dm], 0, 0, 0);
      }
    }
    __syncthreads();
  }

  // epilogue: O[q][d] = acc/l
  float inv = 1.f / l_run;
  bf16* op = O + (size_t)(brow + qbase + q_loc) * NE + h * 64;
  #pragma unroll
  for (int dm = 0; dm < 4; ++dm)
    #pragma unroll
    for (int ep = 0; ep < 2; ++ep) {
      int d = dm * 16 + g * 4 + ep * 2;
      unsigned u = (unsigned)bfbits(acc[dm][2 * ep] * inv) |
                   ((unsigned)bfbits(acc[dm][2 * ep + 1] * inv) << 16);
      *(unsigned*)((unsigned short*)op + d) = u;
    }
}

// ---------------- per-row NLL ----------------
__global__ __launch_bounds__(256) void nll_kernel(
    const float* __restrict__ logits, const int* __restrict__ targets,
    float* __restrict__ nll)
{
  int row = blockIdx.x, tid = threadIdx.x;
  const float* lr = logits + (size_t)row * NV;
  float m = -1e30f, s = 0.f;
  for (int v = tid; v < NV; v += 256) {
    float x = lr[v];
    if (x > m) { s = s * __expf(m - x) + 1.f; m = x; }
    else       { s += __expf(x - m); }
  }
  #pragma unroll
  for (int o = 32; o > 0; o >>= 1) {
    float m2 = __shfl_xor(m, o), s2 = __shfl_xor(s, o);
    float M = fmaxf(m, m2);
    s = s * __expf(m - M) + s2 * __expf(m2 - M);
    m = M;
  }
  __shared__ float ms[4], ss[4];
  if ((tid & 63) == 0) { ms[tid >> 6] = m; ss[tid >> 6] = s; }
  __syncthreads();
  if (tid == 0) {
    float M = fmaxf(fmaxf(ms[0], ms[1]), fmaxf(ms[2], ms[3]));
    float S = ss[0] * __expf(ms[0] - M) + ss[1] * __expf(ms[1] - M)
            + ss[2] * __expf(ms[2] - M) + ss[3] * __expf(ms[3] - M);
    float tgt = lr[targets[row]];
    nll[row] = -(tgt - M - logf(S));
  }
}

__global__ __launch_bounds__(256) void loss_kernel(
    const float* __restrict__ nll, float* __restrict__ out)
{
  int tid = threadIdx.x;
  float s = 0.f;
  for (int i = tid; i < NTOK; i += 256) s += nll[i];
  #pragma unroll
  for (int o = 32; o > 0; o >>= 1) s += __shfl_xor(s, o);
  __shared__ float red[4];
  if ((tid & 63) == 0) red[tid >> 6] = s;
  __syncthreads();
  if (tid == 0) out[0] = (red[0] + red[1] + red[2] + red[3]) * (1.f / NTOK);
}

// ---------------- host ----------------
static inline void gemm(const bf16* A, const bf16* BT,
                        float* Cf, bf16* Cbf,
                        const float* bias, const float* Rres,
                        int M, int N, int Npad, int K, int relu, hipStream_t st)
{
  dim3 g(Npad / BN, M / BM);
  gemm_bf<<<g, dim3(256), 0, st>>>(A, BT, Cf, Cbf, bias, Rres, M, N, K, relu);
}

extern "C" void kernel_launch(void* const* d_in, const int* in_sizes, int n_in,
                              void* d_out, int out_size, void* d_ws, size_t ws_size,
                              hipStream_t stream)
{
  const int*   idx     = (const int*)  d_in[0];
  const int*   targets = (const int*)  d_in[1];
  const float* tok_emb = (const float*)d_in[2];
  const float* pos_emb = (const float*)d_in[3];
  const float* Wq      = (const float*)d_in[4];
  const float* Wk      = (const float*)d_in[5];
  const float* Wv      = (const float*)d_in[6];
  const float* Wo      = (const float*)d_in[7];
  const float* bo      = (const float*)d_in[8];
  const float* ln1_s   = (const float*)d_in[9];
  const float* ln1_b   = (const float*)d_in[10];
  const float* ln2_s   = (const float*)d_in[11];
  const float* ln2_b   = (const float*)d_in[12];
  const float* W1      = (const float*)d_in[13];
  const float* b1      = (const float*)d_in[14];
  const float* W2      = (const float*)d_in[15];
  const float* b2      = (const float*)d_in[16];
  const float* lnf_s   = (const float*)d_in[17];
  const float* lnf_b   = (const float*)d_in[18];
  const float* Wlm     = (const float*)d_in[19];
  const float* blm     = (const float*)d_in[20];
  float* out = (float*)d_out;

  const size_t XE = (size_t)NTOK * NE;
  char* p = (char*)d_ws;
  float* x    = (float*)p;          p += XE * 4;
  bf16* h_bf  = (bf16*)p;           p += XE * 2;
  bf16* q_bf  = (bf16*)p;           p += XE * 2;
  bf16* k_bf  = (bf16*)p;           p += XE * 2;
  bf16* v_bf  = (bf16*)p;           p += XE * 2;
  bf16* att_bf= (bf16*)p;           p += XE * 2;
  bf16* f_bf  = (bf16*)p;           p += (size_t)NTOK * NFF * 2;
  bf16* wtq   = (bf16*)p;           p += (size_t)NE * NE * 2;
  bf16* wtk   = (bf16*)p;           p += (size_t)NE * NE * 2;
  bf16* wtv   = (bf16*)p;           p += (size_t)NE * NE * 2;
  bf16* wto   = (bf16*)p;           p += (size_t)NE * NE * 2;
  bf16* wt1   = (bf16*)p;           p += (size_t)NFF * NE * 2;
  bf16* wt2   = (bf16*)p;           p += (size_t)NE * NFF * 2;
  bf16* wtlm  = (bf16*)p;           p += (size_t)NVP * NE * 2;
  float* nll  = (float*)p;          p += (size_t)NTOK * 4;

  embed_kernel<<<dim3(NTOK), dim3(256), 0, stream>>>(idx, tok_emb, pos_emb, x);

  for (int l = 0; l < NL; ++l) {
    const float* wq_l = Wq + (size_t)l * NH * NE * NHS;
    const float* wk_l = Wk + (size_t)l * NH * NE * NHS;
    const float* wv_l = Wv + (size_t)l * NH * NE * NHS;
    const float* wo_l = Wo + (size_t)l * NE * NE;
    const float* w1_l = W1 + (size_t)l * NE * NFF;
    const float* w2_l = W2 + (size_t)l * NFF * NE;

    ln_kernel<<<dim3(NTOK), dim3(256), 0, stream>>>(x, ln1_s + l*NE, ln1_b + l*NE, h_bf);

    tconv_kernel<<<dim3(2, 24, NH), dim3(256), 0, stream>>>(wq_l, wtq, NE, NHS, NHS);
    tconv_kernel<<<dim3(2, 24, NH), dim3(256), 0, stream>>>(wk_l, wtk, NE, NHS, NHS);
    tconv_kernel<<<dim3(2, 24, NH), dim3(256), 0, stream>>>(wv_l, wtv, NE, NHS, NHS);
    tconv_kernel<<<dim3(24, 24, 1), dim3(256), 0, stream>>>(wo_l, wto, NE, NE, NE);
    tconv_kernel<<<dim3(96, 24, 1), dim3(256), 0, stream>>>(w1_l, wt1, NE, NFF, NFF);
    tconv_kernel<<<dim3(24, 96, 1), dim3(256), 0, stream>>>(w2_l, wt2, NFF, NE, NE);

    gemm(h_bf, wtq, nullptr, q_bf, nullptr, nullptr, NTOK, NE, NE, NE, 0, stream);
    gemm(h_bf, wtk, nullptr, k_bf, nullptr, nullptr, NTOK, NE, NE, NE, 0, stream);
    gemm(h_bf, wtv, nullptr, v_bf, nullptr, nullptr, NTOK, NE, NE, NE, 0, stream);

    fattn_kernel<<<dim3(NT / 64, NH, NB), dim3(256), 0, stream>>>(q_bf, k_bf, v_bf, att_bf);

    gemm(att_bf, wto, x, nullptr, bo + l*NE, x, NTOK, NE, NE, NE, 0, stream);

    ln_kernel<<<dim3(NTOK), dim3(256), 0, stream>>>(x, ln2_s + l*NE, ln2_b + l*NE, h_bf);

    gemm(h_bf, wt1, nullptr, f_bf, b1 + l*NFF, nullptr, NTOK, NFF, NFF, NE, 1, stream);
    gemm(f_bf, wt2, x, nullptr, b2 + l*NE, x, NTOK, NE, NE, NFF, 0, stream);
  }

  ln_kernel<<<dim3(NTOK), dim3(256), 0, stream>>>(x, lnf_s, lnf_b, h_bf);
  tconv_kernel<<<dim3(NVP/32, 24, 1), dim3(256), 0, stream>>>(Wlm, wtlm, NE, NV, NVP);
  gemm(h_bf, wtlm, out, nullptr, blm, nullptr, NTOK, NV, NVP, NE, 0, stream);

  nll_kernel<<<dim3(NTOK), dim3(256), 0, stream>>>(out, targets, nll);
  loss_kernel<<<dim3(1), dim3(256), 0, stream>>>(nll, out + (size_t)NTOK * NV);
}

// Round 4
// 2634.047 us; speedup vs baseline: 5.5959x; 1.0916x over previous
//
#include <hip/hip_runtime.h>
#include <hip/hip_bf16.h>
#include <cstdint>
#include <cstddef>

#define NB 4
#define NT 1024
#define NE 768
#define NH 12
#define NHS 64
#define NL 6
#define NFF 3072
#define NV 50257
#define NVP 50304          // 50257 padded to /128
#define NTOK (NB*NT)       // 4096
#define NCB_LM (NVP/128)   // 393 col-blocks in LM head
#define QKVS 2304          // fused QKV row stride

typedef __attribute__((ext_vector_type(8))) short short8;
typedef __attribute__((ext_vector_type(4))) float f32x4;
typedef __hip_bfloat16 bf16;

// ---------------- embedding ----------------
__global__ __launch_bounds__(256) void embed_kernel(
    const int* __restrict__ idx, const float* __restrict__ tok,
    const float* __restrict__ pos, float* __restrict__ x)
{
  int bt = blockIdx.x;
  int token = idx[bt];
  int t = bt & (NT - 1);
  const float* tr = tok + (size_t)token * NE;
  const float* pr = pos + (size_t)t * NE;
  float* xr = x + (size_t)bt * NE;
  for (int i = threadIdx.x; i < NE; i += 256)
    xr[i] = tr[i] + pr[i];
}

// ---------------- layernorm (row = 768), bf16 out ----------------
__global__ __launch_bounds__(256) void ln_kernel(
    const float* __restrict__ in, const float* __restrict__ sc,
    const float* __restrict__ bi, bf16* __restrict__ out)
{
  int row = blockIdx.x, tid = threadIdx.x;
  const float* xr = in + (size_t)row * NE;
  float v0 = xr[tid], v1 = xr[tid + 256], v2 = xr[tid + 512];
  float s = v0 + v1 + v2;
  float ss = v0 * v0 + v1 * v1 + v2 * v2;
  #pragma unroll
  for (int o = 32; o > 0; o >>= 1) {
    s  += __shfl_xor(s, o);
    ss += __shfl_xor(ss, o);
  }
  __shared__ float r1[4], r2[4];
  if ((tid & 63) == 0) { r1[tid >> 6] = s; r2[tid >> 6] = ss; }
  __syncthreads();
  float tot = r1[0] + r1[1] + r1[2] + r1[3];
  float tss = r2[0] + r2[1] + r2[2] + r2[3];
  float mu  = tot * (1.f / NE);
  float var = tss * (1.f / NE) - mu * mu;
  float rs  = rsqrtf(var + 1e-5f);
  bf16* orow = out + (size_t)row * NE;
  orow[tid]       = __float2bfloat16((v0 - mu) * rs * sc[tid]       + bi[tid]);
  orow[tid + 256] = __float2bfloat16((v1 - mu) * rs * sc[tid + 256] + bi[tid + 256]);
  orow[tid + 512] = __float2bfloat16((v2 - mu) * rs * sc[tid + 512] + bi[tid + 512]);
}

// ------- transpose+convert: src f32 [R][Cs] (per z) -> dst bf16 [Cd][R] -------
__global__ __launch_bounds__(256) void tconv_kernel(
    const float* __restrict__ src, bf16* __restrict__ dst,
    int R, int Cs, int Cd)
{
  __shared__ float t[32][33];
  int z = blockIdx.z;
  src += (size_t)z * R * Cs;
  dst += (size_t)z * Cd * R;
  int c0 = blockIdx.x * 32, r0 = blockIdx.y * 32;
  int tx = threadIdx.x & 31, ty = threadIdx.x >> 5;
  #pragma unroll
  for (int i = 0; i < 32; i += 8) {
    int r = r0 + ty + i, c = c0 + tx;
    t[ty + i][tx] = (c < Cs) ? src[(size_t)r * Cs + c] : 0.f;
  }
  __syncthreads();
  #pragma unroll
  for (int i = 0; i < 32; i += 8) {
    int c = c0 + ty + i, r = r0 + tx;
    if (c < Cd) dst[(size_t)c * R + r] = __float2bfloat16(t[tx][ty + i]);
  }
}

// ---------------- bf16 MFMA GEMM (m97 structure) ----------------
// blockIdx.x = row tile (fastest -> consecutive blocks share B panel),
// blockIdx.y = col tile.
// Optional fused per-row softmax partials (pm/ps, one per (row, colblock)).
#define BM 128
#define BN 128
__global__ __launch_bounds__(256) void gemm_bf(
    const bf16* __restrict__ A,
    const bf16* __restrict__ BT,
    float* __restrict__ Cf, bf16* __restrict__ Cbf,
    const float* __restrict__ bias, const float* __restrict__ Rres,
    float* __restrict__ pm, float* __restrict__ ps,
    int M, int N, int K, int relu, int ncb)
{
  __shared__ bf16 As[BM][64];
  __shared__ bf16 Bs[BN][64];
  __shared__ float pm2[128][2], ps2[128][2];
  int tid = threadIdx.x;
  int lane = tid & 63;
  int w = __builtin_amdgcn_readfirstlane(tid >> 6);
  int wr = w >> 1, wc = w & 1;
  int row0 = blockIdx.x * BM;
  int col0 = blockIdx.y * BN;

  f32x4 acc[4][4] = {};

  for (int k0 = 0; k0 < K; k0 += 64) {
    #pragma unroll
    for (int r = 0; r < 4; ++r) {
      int c = r * 256 + w * 64 + lane;
      int trow = c >> 3, tcol = (c & 7) << 3;
      const bf16* ga = A  + (size_t)(row0 + trow) * K + k0 + tcol;
      const bf16* gb = BT + (size_t)(col0 + trow) * K + k0 + tcol;
      unsigned lofs = (unsigned)(r * 256 + w * 64) * 16;
      __builtin_amdgcn_global_load_lds(
          (const __attribute__((address_space(1))) void*)ga,
          (__attribute__((address_space(3))) void*)((char*)&As[0][0] + lofs),
          16, 0, 0);
      __builtin_amdgcn_global_load_lds(
          (const __attribute__((address_space(1))) void*)gb,
          (__attribute__((address_space(3))) void*)((char*)&Bs[0][0] + lofs),
          16, 0, 0);
    }
    __syncthreads();
    int g8 = (lane >> 4) << 3;
    #pragma unroll
    for (int kk = 0; kk < 64; kk += 32) {
      short8 a[4], b[4];
      #pragma unroll
      for (int m = 0; m < 4; ++m)
        a[m] = *(const short8*)&As[wr * 64 + m * 16 + (lane & 15)][kk + g8];
      #pragma unroll
      for (int n = 0; n < 4; ++n)
        b[n] = *(const short8*)&Bs[wc * 64 + n * 16 + (lane & 15)][kk + g8];
      #pragma unroll
      for (int m = 0; m < 4; ++m)
        #pragma unroll
        for (int n = 0; n < 4; ++n)
          acc[m][n] = __builtin_amdgcn_mfma_f32_16x16x32_bf16(a[m], b[n], acc[m][n], 0, 0, 0);
    }
    __syncthreads();
  }

  int cr = lane >> 4;
  int cc = lane & 15;
  #pragma unroll
  for (int m = 0; m < 4; ++m) {
    #pragma unroll
    for (int n = 0; n < 4; ++n) {
      int col = col0 + wc * 64 + n * 16 + cc;
      if (col >= N) continue;
      float bv = bias ? bias[col] : 0.f;
      #pragma unroll
      for (int e = 0; e < 4; ++e) {
        int row = row0 + wr * 64 + m * 16 + cr * 4 + e;
        float v = acc[m][n][e] + bv;
        size_t off = (size_t)row * N + col;
        if (Rres) v += Rres[off];
        if (relu) v = fmaxf(v, 0.f);
        if (Cf)  Cf[off] = v;
        if (Cbf) Cbf[off] = __float2bfloat16(v);
      }
    }
  }

  // fused per-row (max, sum-exp) partials over this block's 128 cols
  if (pm) {
    #pragma unroll
    for (int m = 0; m < 4; ++m) {
      #pragma unroll
      for (int e = 0; e < 4; ++e) {
        float val[4];
        float vmax = -1e30f;
        #pragma unroll
        for (int n = 0; n < 4; ++n) {
          int col = col0 + wc * 64 + n * 16 + cc;
          val[n] = (col < N) ? (acc[m][n][e] + (bias ? bias[col] : 0.f)) : -1e30f;
          vmax = fmaxf(vmax, val[n]);
        }
        vmax = fmaxf(vmax, __shfl_xor(vmax, 1));
        vmax = fmaxf(vmax, __shfl_xor(vmax, 2));
        vmax = fmaxf(vmax, __shfl_xor(vmax, 4));
        vmax = fmaxf(vmax, __shfl_xor(vmax, 8));
        float ssum = 0.f;
        #pragma unroll
        for (int n = 0; n < 4; ++n) {
          int col = col0 + wc * 64 + n * 16 + cc;
          ssum += (col < N) ? __expf(val[n] - vmax) : 0.f;
        }
        ssum += __shfl_xor(ssum, 1);
        ssum += __shfl_xor(ssum, 2);
        ssum += __shfl_xor(ssum, 4);
        ssum += __shfl_xor(ssum, 8);
        if (cc == 0) {
          int rl = wr * 64 + m * 16 + cr * 4 + e;
          pm2[rl][wc] = vmax;
          ps2[rl][wc] = ssum;
        }
      }
    }
    __syncthreads();
    for (int i = tid; i < 128; i += 256) {
      float m0 = pm2[i][0], m1 = pm2[i][1];
      float s0 = ps2[i][0], s1 = ps2[i][1];
      float Mv = fmaxf(m0, m1);
      float Sv = s0 * __expf(m0 - Mv) + s1 * __expf(m1 - Mv);
      size_t o = (size_t)(row0 + i) * ncb + blockIdx.y;
      pm[o] = Mv;
      ps[o] = Sv;
    }
  }
}

// ---------------- flash attention, MFMA, online softmax ----------------
static __device__ inline unsigned short bfbits(float x) {
  bf16 h = __float2bfloat16(x);
  return *reinterpret_cast<unsigned short*>(&h);
}

__global__ __launch_bounds__(256) void fattn_kernel(
    const bf16* __restrict__ QKV, bf16* __restrict__ O)
{
  __shared__ unsigned short Ks[64][72];
  __shared__ unsigned short Vt[64][72];
  __shared__ unsigned short Pl[4][16][72];
  int qt = blockIdx.x, h = blockIdx.y, b = blockIdx.z;
  int tid = threadIdx.x;
  int lane = tid & 63;
  int w = tid >> 6;
  int l15 = lane & 15, g = lane >> 4;
  int brow = b * NT;
  int qbase = qt * 64;
  int q_loc = w * 16 + l15;

  short8 bq[2];
  {
    const bf16* qp = QKV + (size_t)(brow + qbase + q_loc) * QKVS + h * 64 + g * 8;
    bq[0] = *(const short8*)qp;
    bq[1] = *(const short8*)(qp + 32);
  }

  float m_run = -1e30f, l_run = 0.f;
  f32x4 acc[4] = {};

  for (int kt = 0; kt <= qt; ++kt) {
    int s0 = kt * 64;
    #pragma unroll
    for (int i = 0; i < 2; ++i) {
      int c = tid + i * 256;
      int row = c >> 3, colg = (c & 7) * 8;
      const bf16* kp = QKV + (size_t)(brow + s0 + row) * QKVS + NE + h * 64 + colg;
      const bf16* vp = QKV + (size_t)(brow + s0 + row) * QKVS + 2 * NE + h * 64 + colg;
      short8 kv = *(const short8*)kp;
      short8 vv = *(const short8*)vp;
      *(short8*)&Ks[row][colg] = kv;
      #pragma unroll
      for (int j = 0; j < 8; ++j)
        Vt[colg + j][row] = (unsigned short)vv[j];
    }
    __syncthreads();

    f32x4 sf[4] = {};
    #pragma unroll
    for (int kk = 0; kk < 2; ++kk) {
      #pragma unroll
      for (int m = 0; m < 4; ++m) {
        short8 a = *(const short8*)&Ks[m * 16 + l15][kk * 32 + g * 8];
        sf[m] = __builtin_amdgcn_mfma_f32_16x16x32_bf16(a, bq[kk], sf[m], 0, 0, 0);
      }
    }

    float sv[4][4];
    float mx = -1e30f;
    bool diag = (kt == qt);
    #pragma unroll
    for (int m = 0; m < 4; ++m)
      #pragma unroll
      for (int e = 0; e < 4; ++e) {
        float v = sf[m][e] * 0.125f;
        if (diag) {
          int sl = m * 16 + g * 4 + e;
          if (sl > q_loc) v = -1e30f;
        }
        sv[m][e] = v;
        mx = fmaxf(mx, v);
      }
    mx = fmaxf(mx, __shfl_xor(mx, 16));
    mx = fmaxf(mx, __shfl_xor(mx, 32));
    float m_new = fmaxf(m_run, mx);
    float p[4][4];
    float rs = 0.f;
    #pragma unroll
    for (int m = 0; m < 4; ++m)
      #pragma unroll
      for (int e = 0; e < 4; ++e) {
        float pe = __expf(sv[m][e] - m_new);
        p[m][e] = pe;
        rs += pe;
      }
    rs += __shfl_xor(rs, 16);
    rs += __shfl_xor(rs, 32);
    float sc_old = __expf(m_run - m_new);
    l_run = l_run * sc_old + rs;
    m_run = m_new;
    #pragma unroll
    for (int dm = 0; dm < 4; ++dm)
      #pragma unroll
      for (int e = 0; e < 4; ++e)
        acc[dm][e] *= sc_old;

    #pragma unroll
    for (int m = 0; m < 4; ++m)
      #pragma unroll
      for (int ep = 0; ep < 2; ++ep) {
        unsigned u = (unsigned)bfbits(p[m][2 * ep]) |
                     ((unsigned)bfbits(p[m][2 * ep + 1]) << 16);
        *(unsigned*)&Pl[w][l15][m * 16 + g * 4 + ep * 2] = u;
      }

    #pragma unroll
    for (int ks = 0; ks < 2; ++ks) {
      short8 pb = *(const short8*)&Pl[w][l15][ks * 32 + g * 8];
      #pragma unroll
      for (int dm = 0; dm < 4; ++dm) {
        short8 av = *(const short8*)&Vt[dm * 16 + l15][ks * 32 + g * 8];
        acc[dm] = __builtin_amdgcn_mfma_f32_16x16x32_bf16(av, pb, acc[dm], 0, 0, 0);
      }
    }
    __syncthreads();
  }

  float inv = 1.f / l_run;
  bf16* op = O + (size_t)(brow + qbase + q_loc) * NE + h * 64;
  #pragma unroll
  for (int dm = 0; dm < 4; ++dm)
    #pragma unroll
    for (int ep = 0; ep < 2; ++ep) {
      int d = dm * 16 + g * 4 + ep * 2;
      unsigned u = (unsigned)bfbits(acc[dm][2 * ep] * inv) |
                   ((unsigned)bfbits(acc[dm][2 * ep + 1] * inv) << 16);
      *(unsigned*)((unsigned short*)op + d) = u;
    }
}

// ---------------- NLL from fused partials ----------------
__global__ __launch_bounds__(128) void nll_finish(
    const float* __restrict__ pm, const float* __restrict__ ps,
    const float* __restrict__ logits, const int* __restrict__ targets,
    float* __restrict__ nll)
{
  int row = blockIdx.x, tid = threadIdx.x;
  float m = -1e30f, s = 0.f;
  for (int i = tid; i < NCB_LM; i += 128) {
    float pmv = pm[(size_t)row * NCB_LM + i];
    float psv = ps[(size_t)row * NCB_LM + i];
    float Mv = fmaxf(m, pmv);
    s = s * __expf(m - Mv) + psv * __expf(pmv - Mv);
    m = Mv;
  }
  #pragma unroll
  for (int o = 32; o > 0; o >>= 1) {
    float m2 = __shfl_xor(m, o), s2 = __shfl_xor(s, o);
    float Mv = fmaxf(m, m2);
    s = s * __expf(m - Mv) + s2 * __expf(m2 - Mv);
    m = Mv;
  }
  __shared__ float ms[2], ss[2];
  if ((tid & 63) == 0) { ms[tid >> 6] = m; ss[tid >> 6] = s; }
  __syncthreads();
  if (tid == 0) {
    float Mv = fmaxf(ms[0], ms[1]);
    float Sv = ss[0] * __expf(ms[0] - Mv) + ss[1] * __expf(ms[1] - Mv);
    float tgt = logits[(size_t)row * NV + targets[row]];
    nll[row] = -(tgt - Mv - logf(Sv));
  }
}

__global__ __launch_bounds__(256) void loss_kernel(
    const float* __restrict__ nll, float* __restrict__ out)
{
  int tid = threadIdx.x;
  float s = 0.f;
  for (int i = tid; i < NTOK; i += 256) s += nll[i];
  #pragma unroll
  for (int o = 32; o > 0; o >>= 1) s += __shfl_xor(s, o);
  __shared__ float red[4];
  if ((tid & 63) == 0) red[tid >> 6] = s;
  __syncthreads();
  if (tid == 0) out[0] = (red[0] + red[1] + red[2] + red[3]) * (1.f / NTOK);
}

// ---------------- host ----------------
static inline void gemm(const bf16* A, const bf16* BT,
                        float* Cf, bf16* Cbf,
                        const float* bias, const float* Rres,
                        float* pm, float* ps,
                        int M, int N, int Npad, int K, int relu, hipStream_t st)
{
  dim3 g(M / BM, Npad / BN);
  gemm_bf<<<g, dim3(256), 0, st>>>(A, BT, Cf, Cbf, bias, Rres, pm, ps,
                                   M, N, K, relu, Npad / BN);
}

extern "C" void kernel_launch(void* const* d_in, const int* in_sizes, int n_in,
                              void* d_out, int out_size, void* d_ws, size_t ws_size,
                              hipStream_t stream)
{
  const int*   idx     = (const int*)  d_in[0];
  const int*   targets = (const int*)  d_in[1];
  const float* tok_emb = (const float*)d_in[2];
  const float* pos_emb = (const float*)d_in[3];
  const float* Wq      = (const float*)d_in[4];
  const float* Wk      = (const float*)d_in[5];
  const float* Wv      = (const float*)d_in[6];
  const float* Wo      = (const float*)d_in[7];
  const float* bo      = (const float*)d_in[8];
  const float* ln1_s   = (const float*)d_in[9];
  const float* ln1_b   = (const float*)d_in[10];
  const float* ln2_s   = (const float*)d_in[11];
  const float* ln2_b   = (const float*)d_in[12];
  const float* W1      = (const float*)d_in[13];
  const float* b1      = (const float*)d_in[14];
  const float* W2      = (const float*)d_in[15];
  const float* b2      = (const float*)d_in[16];
  const float* lnf_s   = (const float*)d_in[17];
  const float* lnf_b   = (const float*)d_in[18];
  const float* Wlm     = (const float*)d_in[19];
  const float* blm     = (const float*)d_in[20];
  float* out = (float*)d_out;

  const size_t XE = (size_t)NTOK * NE;
  char* p = (char*)d_ws;
  float* x     = (float*)p;         p += XE * 4;
  bf16* h_bf   = (bf16*)p;          p += XE * 2;
  bf16* qkv_bf = (bf16*)p;          p += (size_t)NTOK * QKVS * 2;
  bf16* att_bf = (bf16*)p;          p += XE * 2;
  bf16* f_bf   = (bf16*)p;          p += (size_t)NTOK * NFF * 2;
  bf16* wqkv   = (bf16*)p;          p += (size_t)QKVS * NE * 2;
  bf16* wto    = (bf16*)p;          p += (size_t)NE * NE * 2;
  bf16* wt1    = (bf16*)p;          p += (size_t)NFF * NE * 2;
  bf16* wt2    = (bf16*)p;          p += (size_t)NE * NFF * 2;
  bf16* wtlm   = (bf16*)p;          p += (size_t)NVP * NE * 2;
  float* pmb   = (float*)p;         p += (size_t)NTOK * NCB_LM * 4;
  float* psb   = (float*)p;         p += (size_t)NTOK * NCB_LM * 4;
  float* nll   = (float*)p;         p += (size_t)NTOK * 4;

  embed_kernel<<<dim3(NTOK), dim3(256), 0, stream>>>(idx, tok_emb, pos_emb, x);

  for (int l = 0; l < NL; ++l) {
    const float* wq_l = Wq + (size_t)l * NH * NE * NHS;
    const float* wk_l = Wk + (size_t)l * NH * NE * NHS;
    const float* wv_l = Wv + (size_t)l * NH * NE * NHS;
    const float* wo_l = Wo + (size_t)l * NE * NE;
    const float* w1_l = W1 + (size_t)l * NE * NFF;
    const float* w2_l = W2 + (size_t)l * NFF * NE;

    ln_kernel<<<dim3(NTOK), dim3(256), 0, stream>>>(x, ln1_s + l*NE, ln1_b + l*NE, h_bf);

    // fused QKV weight: rows 0..767 = Q, 768..1535 = K, 1536..2303 = V
    tconv_kernel<<<dim3(2, 24, NH), dim3(256), 0, stream>>>(wq_l, wqkv, NE, NHS, NHS);
    tconv_kernel<<<dim3(2, 24, NH), dim3(256), 0, stream>>>(wk_l, wqkv + (size_t)NE*NE, NE, NHS, NHS);
    tconv_kernel<<<dim3(2, 24, NH), dim3(256), 0, stream>>>(wv_l, wqkv + (size_t)2*NE*NE, NE, NHS, NHS);
    tconv_kernel<<<dim3(24, 24, 1), dim3(256), 0, stream>>>(wo_l, wto, NE, NE, NE);
    tconv_kernel<<<dim3(96, 24, 1), dim3(256), 0, stream>>>(w1_l, wt1, NE, NFF, NFF);
    tconv_kernel<<<dim3(24, 96, 1), dim3(256), 0, stream>>>(w2_l, wt2, NFF, NE, NE);

    gemm(h_bf, wqkv, nullptr, qkv_bf, nullptr, nullptr, nullptr, nullptr,
         NTOK, QKVS, QKVS, NE, 0, stream);

    fattn_kernel<<<dim3(NT / 64, NH, NB), dim3(256), 0, stream>>>(qkv_bf, att_bf);

    gemm(att_bf, wto, x, nullptr, bo + l*NE, x, nullptr, nullptr,
         NTOK, NE, NE, NE, 0, stream);

    ln_kernel<<<dim3(NTOK), dim3(256), 0, stream>>>(x, ln2_s + l*NE, ln2_b + l*NE, h_bf);

    gemm(h_bf, wt1, nullptr, f_bf, b1 + l*NFF, nullptr, nullptr, nullptr,
         NTOK, NFF, NFF, NE, 1, stream);
    gemm(f_bf, wt2, x, nullptr, b2 + l*NE, x, nullptr, nullptr,
         NTOK, NE, NE, NFF, 0, stream);
  }

  ln_kernel<<<dim3(NTOK), dim3(256), 0, stream>>>(x, lnf_s, lnf_b, h_bf);
  tconv_kernel<<<dim3(NVP/32, 24, 1), dim3(256), 0, stream>>>(Wlm, wtlm, NE, NV, NVP);
  gemm(h_bf, wtlm, out, nullptr, blm, nullptr, pmb, psb,
       NTOK, NV, NVP, NE, 0, stream);

  nll_finish<<<dim3(NTOK), dim3(128), 0, stream>>>(pmb, psb, out, targets, nll);
  loss_kernel<<<dim3(1), dim3(256), 0, stream>>>(nll, out + (size_t)NTOK * NV);
}

// Round 5
// 2463.963 us; speedup vs baseline: 5.9821x; 1.0690x over previous
//
#include <hip/hip_runtime.h>
#include <hip/hip_bf16.h>
#include <cstdint>
#include <cstddef>

#define NB 4
#define NT 1024
#define NE 768
#define NH 12
#define NHS 64
#define NL 6
#define NFF 3072
#define NV 50257
#define NVP 50304          // 50257 padded to /128
#define NTOK (NB*NT)       // 4096
#define NCB_LM (NVP/128)   // 393 col-blocks in LM head
#define QKVS 2304          // fused QKV row stride

typedef __attribute__((ext_vector_type(8))) short short8;
typedef __attribute__((ext_vector_type(4))) float f32x4;
typedef __hip_bfloat16 bf16;

// ---------------- embedding ----------------
__global__ __launch_bounds__(256) void embed_kernel(
    const int* __restrict__ idx, const float* __restrict__ tok,
    const float* __restrict__ pos, float* __restrict__ x)
{
  int bt = blockIdx.x;
  int token = idx[bt];
  int t = bt & (NT - 1);
  const float* tr = tok + (size_t)token * NE;
  const float* pr = pos + (size_t)t * NE;
  float* xr = x + (size_t)bt * NE;
  for (int i = threadIdx.x; i < NE; i += 256)
    xr[i] = tr[i] + pr[i];
}

// ---------------- layernorm (row = 768), bf16 out ----------------
__global__ __launch_bounds__(256) void ln_kernel(
    const float* __restrict__ in, const float* __restrict__ sc,
    const float* __restrict__ bi, bf16* __restrict__ out)
{
  int row = blockIdx.x, tid = threadIdx.x;
  const float* xr = in + (size_t)row * NE;
  float v0 = xr[tid], v1 = xr[tid + 256], v2 = xr[tid + 512];
  float s = v0 + v1 + v2;
  float ss = v0 * v0 + v1 * v1 + v2 * v2;
  #pragma unroll
  for (int o = 32; o > 0; o >>= 1) {
    s  += __shfl_xor(s, o);
    ss += __shfl_xor(ss, o);
  }
  __shared__ float r1[4], r2[4];
  if ((tid & 63) == 0) { r1[tid >> 6] = s; r2[tid >> 6] = ss; }
  __syncthreads();
  float tot = r1[0] + r1[1] + r1[2] + r1[3];
  float tss = r2[0] + r2[1] + r2[2] + r2[3];
  float mu  = tot * (1.f / NE);
  float var = tss * (1.f / NE) - mu * mu;
  float rs  = rsqrtf(var + 1e-5f);
  bf16* orow = out + (size_t)row * NE;
  orow[tid]       = __float2bfloat16((v0 - mu) * rs * sc[tid]       + bi[tid]);
  orow[tid + 256] = __float2bfloat16((v1 - mu) * rs * sc[tid + 256] + bi[tid + 256]);
  orow[tid + 512] = __float2bfloat16((v2 - mu) * rs * sc[tid + 512] + bi[tid + 512]);
}

// ------- transpose+convert: src f32 [R][Cs] (per z) -> dst bf16 [Cd][R] -------
__global__ __launch_bounds__(256) void tconv_kernel(
    const float* __restrict__ src, bf16* __restrict__ dst,
    int R, int Cs, int Cd)
{
  __shared__ float t[32][33];
  int z = blockIdx.z;
  src += (size_t)z * R * Cs;
  dst += (size_t)z * Cd * R;
  int c0 = blockIdx.x * 32, r0 = blockIdx.y * 32;
  int tx = threadIdx.x & 31, ty = threadIdx.x >> 5;
  #pragma unroll
  for (int i = 0; i < 32; i += 8) {
    int r = r0 + ty + i, c = c0 + tx;
    t[ty + i][tx] = (c < Cs) ? src[(size_t)r * Cs + c] : 0.f;
  }
  __syncthreads();
  #pragma unroll
  for (int i = 0; i < 32; i += 8) {
    int c = c0 + ty + i, r = r0 + tx;
    if (c < Cd) dst[(size_t)c * R + r] = __float2bfloat16(t[tx][ty + i]);
  }
}

// ---------------- bf16 MFMA GEMM (m97 structure + T2 LDS XOR-swizzle) ----------------
// x = col tile (fastest), y = row tile (col-fastest: consecutive blocks share A panel).
// LDS swizzle (rule #21): linear global_load_lds dest + pre-swizzled global source
// chunk (chunk ^= row&7) + same XOR on ds_read address. Kills the 16-way bank
// conflict of the 128B-stride row-major tile.
#define BM 128
#define BN 128
__global__ __launch_bounds__(256) void gemm_bf(
    const bf16* __restrict__ A,
    const bf16* __restrict__ BT,
    float* __restrict__ Cf, bf16* __restrict__ Cbf,
    const float* __restrict__ bias, const float* __restrict__ Rres,
    float* __restrict__ pm, float* __restrict__ ps,
    int M, int N, int K, int relu, int ncb)
{
  __shared__ bf16 As[BM][64];
  __shared__ bf16 Bs[BN][64];
  __shared__ float pm2[128][2], ps2[128][2];
  int tid = threadIdx.x;
  int lane = tid & 63;
  int w = __builtin_amdgcn_readfirstlane(tid >> 6);
  int wr = w >> 1, wc = w & 1;
  int row0 = blockIdx.y * BM;
  int col0 = blockIdx.x * BN;

  f32x4 acc[4][4] = {};

  for (int k0 = 0; k0 < K; k0 += 64) {
    #pragma unroll
    for (int r = 0; r < 4; ++r) {
      int c = r * 256 + w * 64 + lane;       // 16B-chunk index 0..1023
      int trow = c >> 3;                      // tile row 0..127
      int schunk = (c & 7) ^ (trow & 7);      // pre-swizzled source chunk
      int tcol = schunk << 3;                 // element offset within row
      const bf16* ga = A  + (size_t)(row0 + trow) * K + k0 + tcol;
      const bf16* gb = BT + (size_t)(col0 + trow) * K + k0 + tcol;
      unsigned lofs = (unsigned)c * 16;       // linear LDS dest
      __builtin_amdgcn_global_load_lds(
          (const __attribute__((address_space(1))) void*)ga,
          (__attribute__((address_space(3))) void*)((char*)&As[0][0] + lofs),
          16, 0, 0);
      __builtin_amdgcn_global_load_lds(
          (const __attribute__((address_space(1))) void*)gb,
          (__attribute__((address_space(3))) void*)((char*)&Bs[0][0] + lofs),
          16, 0, 0);
    }
    __syncthreads();
    int l15 = lane & 15;
    int g8 = (lane >> 4) << 3;
    int sx = (l15 & 7) << 3;                  // read-side swizzle (element XOR)
    #pragma unroll
    for (int kk = 0; kk < 64; kk += 32) {
      short8 a[4], b[4];
      #pragma unroll
      for (int m = 0; m < 4; ++m)
        a[m] = *(const short8*)&As[wr * 64 + m * 16 + l15][(kk + g8) ^ sx];
      #pragma unroll
      for (int n = 0; n < 4; ++n)
        b[n] = *(const short8*)&Bs[wc * 64 + n * 16 + l15][(kk + g8) ^ sx];
      #pragma unroll
      for (int m = 0; m < 4; ++m)
        #pragma unroll
        for (int n = 0; n < 4; ++n)
          acc[m][n] = __builtin_amdgcn_mfma_f32_16x16x32_bf16(a[m], b[n], acc[m][n], 0, 0, 0);
    }
    __syncthreads();
  }

  int cr = lane >> 4;
  int cc = lane & 15;
  #pragma unroll
  for (int m = 0; m < 4; ++m) {
    #pragma unroll
    for (int n = 0; n < 4; ++n) {
      int col = col0 + wc * 64 + n * 16 + cc;
      if (col >= N) continue;
      float bv = bias ? bias[col] : 0.f;
      #pragma unroll
      for (int e = 0; e < 4; ++e) {
        int row = row0 + wr * 64 + m * 16 + cr * 4 + e;
        float v = acc[m][n][e] + bv;
        size_t off = (size_t)row * N + col;
        if (Rres) v += Rres[off];
        if (relu) v = fmaxf(v, 0.f);
        if (Cf)  Cf[off] = v;
        if (Cbf) Cbf[off] = __float2bfloat16(v);
      }
    }
  }

  // fused per-row (max, sum-exp) partials over this block's 128 cols
  if (pm) {
    #pragma unroll
    for (int m = 0; m < 4; ++m) {
      #pragma unroll
      for (int e = 0; e < 4; ++e) {
        float val[4];
        float vmax = -1e30f;
        #pragma unroll
        for (int n = 0; n < 4; ++n) {
          int col = col0 + wc * 64 + n * 16 + cc;
          val[n] = (col < N) ? (acc[m][n][e] + (bias ? bias[col] : 0.f)) : -1e30f;
          vmax = fmaxf(vmax, val[n]);
        }
        vmax = fmaxf(vmax, __shfl_xor(vmax, 1));
        vmax = fmaxf(vmax, __shfl_xor(vmax, 2));
        vmax = fmaxf(vmax, __shfl_xor(vmax, 4));
        vmax = fmaxf(vmax, __shfl_xor(vmax, 8));
        float ssum = 0.f;
        #pragma unroll
        for (int n = 0; n < 4; ++n) {
          int col = col0 + wc * 64 + n * 16 + cc;
          ssum += (col < N) ? __expf(val[n] - vmax) : 0.f;
        }
        ssum += __shfl_xor(ssum, 1);
        ssum += __shfl_xor(ssum, 2);
        ssum += __shfl_xor(ssum, 4);
        ssum += __shfl_xor(ssum, 8);
        if (cc == 0) {
          int rl = wr * 64 + m * 16 + cr * 4 + e;
          pm2[rl][wc] = vmax;
          ps2[rl][wc] = ssum;
        }
      }
    }
    __syncthreads();
    for (int i = tid; i < 128; i += 256) {
      float m0 = pm2[i][0], m1 = pm2[i][1];
      float s0 = ps2[i][0], s1 = ps2[i][1];
      float Mv = fmaxf(m0, m1);
      float Sv = s0 * __expf(m0 - Mv) + s1 * __expf(m1 - Mv);
      size_t o = (size_t)(row0 + i) * ncb + blockIdx.x;
      pm[o] = Mv;
      ps[o] = Sv;
    }
  }
}

// ---------------- flash attention, MFMA, online softmax ----------------
static __device__ inline unsigned short bfbits(float x) {
  bf16 h = __float2bfloat16(x);
  return *reinterpret_cast<unsigned short*>(&h);
}

__global__ __launch_bounds__(256) void fattn_kernel(
    const bf16* __restrict__ QKV, bf16* __restrict__ O)
{
  __shared__ unsigned short Ks[64][72];
  __shared__ unsigned short Vt[64][72];
  __shared__ unsigned short Pl[4][16][72];
  int qt = blockIdx.x, h = blockIdx.y, b = blockIdx.z;
  int tid = threadIdx.x;
  int lane = tid & 63;
  int w = tid >> 6;
  int l15 = lane & 15, g = lane >> 4;
  int brow = b * NT;
  int qbase = qt * 64;
  int q_loc = w * 16 + l15;

  short8 bq[2];
  {
    const bf16* qp = QKV + (size_t)(brow + qbase + q_loc) * QKVS + h * 64 + g * 8;
    bq[0] = *(const short8*)qp;
    bq[1] = *(const short8*)(qp + 32);
  }

  float m_run = -1e30f, l_run = 0.f;
  f32x4 acc[4] = {};

  for (int kt = 0; kt <= qt; ++kt) {
    int s0 = kt * 64;
    #pragma unroll
    for (int i = 0; i < 2; ++i) {
      int c = tid + i * 256;
      int row = c >> 3, colg = (c & 7) * 8;
      const bf16* kp = QKV + (size_t)(brow + s0 + row) * QKVS + NE + h * 64 + colg;
      const bf16* vp = QKV + (size_t)(brow + s0 + row) * QKVS + 2 * NE + h * 64 + colg;
      short8 kv = *(const short8*)kp;
      short8 vv = *(const short8*)vp;
      *(short8*)&Ks[row][colg] = kv;
      #pragma unroll
      for (int j = 0; j < 8; ++j)
        Vt[colg + j][row] = (unsigned short)vv[j];
    }
    __syncthreads();

    f32x4 sf[4] = {};
    #pragma unroll
    for (int kk = 0; kk < 2; ++kk) {
      #pragma unroll
      for (int m = 0; m < 4; ++m) {
        short8 a = *(const short8*)&Ks[m * 16 + l15][kk * 32 + g * 8];
        sf[m] = __builtin_amdgcn_mfma_f32_16x16x32_bf16(a, bq[kk], sf[m], 0, 0, 0);
      }
    }

    float sv[4][4];
    float mx = -1e30f;
    bool diag = (kt == qt);
    #pragma unroll
    for (int m = 0; m < 4; ++m)
      #pragma unroll
      for (int e = 0; e < 4; ++e) {
        float v = sf[m][e] * 0.125f;
        if (diag) {
          int sl = m * 16 + g * 4 + e;
          if (sl > q_loc) v = -1e30f;
        }
        sv[m][e] = v;
        mx = fmaxf(mx, v);
      }
    mx = fmaxf(mx, __shfl_xor(mx, 16));
    mx = fmaxf(mx, __shfl_xor(mx, 32));
    float m_new = fmaxf(m_run, mx);
    float p[4][4];
    float rs = 0.f;
    #pragma unroll
    for (int m = 0; m < 4; ++m)
      #pragma unroll
      for (int e = 0; e < 4; ++e) {
        float pe = __expf(sv[m][e] - m_new);
        p[m][e] = pe;
        rs += pe;
      }
    rs += __shfl_xor(rs, 16);
    rs += __shfl_xor(rs, 32);
    float sc_old = __expf(m_run - m_new);
    l_run = l_run * sc_old + rs;
    m_run = m_new;
    #pragma unroll
    for (int dm = 0; dm < 4; ++dm)
      #pragma unroll
      for (int e = 0; e < 4; ++e)
        acc[dm][e] *= sc_old;

    #pragma unroll
    for (int m = 0; m < 4; ++m)
      #pragma unroll
      for (int ep = 0; ep < 2; ++ep) {
        unsigned u = (unsigned)bfbits(p[m][2 * ep]) |
                     ((unsigned)bfbits(p[m][2 * ep + 1]) << 16);
        *(unsigned*)&Pl[w][l15][m * 16 + g * 4 + ep * 2] = u;
      }

    #pragma unroll
    for (int ks = 0; ks < 2; ++ks) {
      short8 pb = *(const short8*)&Pl[w][l15][ks * 32 + g * 8];
      #pragma unroll
      for (int dm = 0; dm < 4; ++dm) {
        short8 av = *(const short8*)&Vt[dm * 16 + l15][ks * 32 + g * 8];
        acc[dm] = __builtin_amdgcn_mfma_f32_16x16x32_bf16(av, pb, acc[dm], 0, 0, 0);
      }
    }
    __syncthreads();
  }

  float inv = 1.f / l_run;
  bf16* op = O + (size_t)(brow + qbase + q_loc) * NE + h * 64;
  #pragma unroll
  for (int dm = 0; dm < 4; ++dm)
    #pragma unroll
    for (int ep = 0; ep < 2; ++ep) {
      int d = dm * 16 + g * 4 + ep * 2;
      unsigned u = (unsigned)bfbits(acc[dm][2 * ep] * inv) |
                   ((unsigned)bfbits(acc[dm][2 * ep + 1] * inv) << 16);
      *(unsigned*)((unsigned short*)op + d) = u;
    }
}

// ---------------- NLL from fused partials ----------------
__global__ __launch_bounds__(128) void nll_finish(
    const float* __restrict__ pm, const float* __restrict__ ps,
    const float* __restrict__ logits, const int* __restrict__ targets,
    float* __restrict__ nll)
{
  int row = blockIdx.x, tid = threadIdx.x;
  float m = -1e30f, s = 0.f;
  for (int i = tid; i < NCB_LM; i += 128) {
    float pmv = pm[(size_t)row * NCB_LM + i];
    float psv = ps[(size_t)row * NCB_LM + i];
    float Mv = fmaxf(m, pmv);
    s = s * __expf(m - Mv) + psv * __expf(pmv - Mv);
    m = Mv;
  }
  #pragma unroll
  for (int o = 32; o > 0; o >>= 1) {
    float m2 = __shfl_xor(m, o), s2 = __shfl_xor(s, o);
    float Mv = fmaxf(m, m2);
    s = s * __expf(m - Mv) + s2 * __expf(m2 - Mv);
    m = Mv;
  }
  __shared__ float ms[2], ss[2];
  if ((tid & 63) == 0) { ms[tid >> 6] = m; ss[tid >> 6] = s; }
  __syncthreads();
  if (tid == 0) {
    float Mv = fmaxf(ms[0], ms[1]);
    float Sv = ss[0] * __expf(ms[0] - Mv) + ss[1] * __expf(ms[1] - Mv);
    float tgt = logits[(size_t)row * NV + targets[row]];
    nll[row] = -(tgt - Mv - logf(Sv));
  }
}

__global__ __launch_bounds__(256) void loss_kernel(
    const float* __restrict__ nll, float* __restrict__ out)
{
  int tid = threadIdx.x;
  float s = 0.f;
  for (int i = tid; i < NTOK; i += 256) s += nll[i];
  #pragma unroll
  for (int o = 32; o > 0; o >>= 1) s += __shfl_xor(s, o);
  __shared__ float red[4];
  if ((tid & 63) == 0) red[tid >> 6] = s;
  __syncthreads();
  if (tid == 0) out[0] = (red[0] + red[1] + red[2] + red[3]) * (1.f / NTOK);
}

// ---------------- host ----------------
static inline void gemm(const bf16* A, const bf16* BT,
                        float* Cf, bf16* Cbf,
                        const float* bias, const float* Rres,
                        float* pm, float* ps,
                        int M, int N, int Npad, int K, int relu, hipStream_t st)
{
  dim3 g(Npad / BN, M / BM);   // x = col tile fastest (round-3 order)
  gemm_bf<<<g, dim3(256), 0, st>>>(A, BT, Cf, Cbf, bias, Rres, pm, ps,
                                   M, N, K, relu, Npad / BN);
}

extern "C" void kernel_launch(void* const* d_in, const int* in_sizes, int n_in,
                              void* d_out, int out_size, void* d_ws, size_t ws_size,
                              hipStream_t stream)
{
  const int*   idx     = (const int*)  d_in[0];
  const int*   targets = (const int*)  d_in[1];
  const float* tok_emb = (const float*)d_in[2];
  const float* pos_emb = (const float*)d_in[3];
  const float* Wq      = (const float*)d_in[4];
  const float* Wk      = (const float*)d_in[5];
  const float* Wv      = (const float*)d_in[6];
  const float* Wo      = (const float*)d_in[7];
  const float* bo      = (const float*)d_in[8];
  const float* ln1_s   = (const float*)d_in[9];
  const float* ln1_b   = (const float*)d_in[10];
  const float* ln2_s   = (const float*)d_in[11];
  const float* ln2_b   = (const float*)d_in[12];
  const float* W1      = (const float*)d_in[13];
  const float* b1      = (const float*)d_in[14];
  const float* W2      = (const float*)d_in[15];
  const float* b2      = (const float*)d_in[16];
  const float* lnf_s   = (const float*)d_in[17];
  const float* lnf_b   = (const float*)d_in[18];
  const float* Wlm     = (const float*)d_in[19];
  const float* blm     = (const float*)d_in[20];
  float* out = (float*)d_out;

  const size_t XE = (size_t)NTOK * NE;
  char* p = (char*)d_ws;
  float* x     = (float*)p;         p += XE * 4;
  bf16* h_bf   = (bf16*)p;          p += XE * 2;
  bf16* qkv_bf = (bf16*)p;          p += (size_t)NTOK * QKVS * 2;
  bf16* att_bf = (bf16*)p;          p += XE * 2;
  bf16* f_bf   = (bf16*)p;          p += (size_t)NTOK * NFF * 2;
  bf16* wqkv   = (bf16*)p;          p += (size_t)QKVS * NE * 2;
  bf16* wto    = (bf16*)p;          p += (size_t)NE * NE * 2;
  bf16* wt1    = (bf16*)p;          p += (size_t)NFF * NE * 2;
  bf16* wt2    = (bf16*)p;          p += (size_t)NE * NFF * 2;
  bf16* wtlm   = (bf16*)p;          p += (size_t)NVP * NE * 2;
  float* pmb   = (float*)p;         p += (size_t)NTOK * NCB_LM * 4;
  float* psb   = (float*)p;         p += (size_t)NTOK * NCB_LM * 4;
  float* nll   = (float*)p;         p += (size_t)NTOK * 4;

  embed_kernel<<<dim3(NTOK), dim3(256), 0, stream>>>(idx, tok_emb, pos_emb, x);

  for (int l = 0; l < NL; ++l) {
    const float* wq_l = Wq + (size_t)l * NH * NE * NHS;
    const float* wk_l = Wk + (size_t)l * NH * NE * NHS;
    const float* wv_l = Wv + (size_t)l * NH * NE * NHS;
    const float* wo_l = Wo + (size_t)l * NE * NE;
    const float* w1_l = W1 + (size_t)l * NE * NFF;
    const float* w2_l = W2 + (size_t)l * NFF * NE;

    ln_kernel<<<dim3(NTOK), dim3(256), 0, stream>>>(x, ln1_s + l*NE, ln1_b + l*NE, h_bf);

    // fused QKV weight: rows 0..767 = Q, 768..1535 = K, 1536..2303 = V
    tconv_kernel<<<dim3(2, 24, NH), dim3(256), 0, stream>>>(wq_l, wqkv, NE, NHS, NHS);
    tconv_kernel<<<dim3(2, 24, NH), dim3(256), 0, stream>>>(wk_l, wqkv + (size_t)NE*NE, NE, NHS, NHS);
    tconv_kernel<<<dim3(2, 24, NH), dim3(256), 0, stream>>>(wv_l, wqkv + (size_t)2*NE*NE, NE, NHS, NHS);
    tconv_kernel<<<dim3(24, 24, 1), dim3(256), 0, stream>>>(wo_l, wto, NE, NE, NE);
    tconv_kernel<<<dim3(96, 24, 1), dim3(256), 0, stream>>>(w1_l, wt1, NE, NFF, NFF);
    tconv_kernel<<<dim3(24, 96, 1), dim3(256), 0, stream>>>(w2_l, wt2, NFF, NE, NE);

    gemm(h_bf, wqkv, nullptr, qkv_bf, nullptr, nullptr, nullptr, nullptr,
         NTOK, QKVS, QKVS, NE, 0, stream);

    fattn_kernel<<<dim3(NT / 64, NH, NB), dim3(256), 0, stream>>>(qkv_bf, att_bf);

    gemm(att_bf, wto, x, nullptr, bo + l*NE, x, nullptr, nullptr,
         NTOK, NE, NE, NE, 0, stream);

    ln_kernel<<<dim3(NTOK), dim3(256), 0, stream>>>(x, ln2_s + l*NE, ln2_b + l*NE, h_bf);

    gemm(h_bf, wt1, nullptr, f_bf, b1 + l*NFF, nullptr, nullptr, nullptr,
         NTOK, NFF, NFF, NE, 1, stream);
    gemm(f_bf, wt2, x, nullptr, b2 + l*NE, x, nullptr, nullptr,
         NTOK, NE, NE, NFF, 0, stream);
  }

  ln_kernel<<<dim3(NTOK), dim3(256), 0, stream>>>(x, lnf_s, lnf_b, h_bf);
  tconv_kernel<<<dim3(NVP/32, 24, 1), dim3(256), 0, stream>>>(Wlm, wtlm, NE, NV, NVP);
  gemm(h_bf, wtlm, out, nullptr, blm, nullptr, pmb, psb,
       NTOK, NV, NVP, NE, 0, stream);

  nll_finish<<<dim3(NTOK), dim3(128), 0, stream>>>(pmb, psb, out, targets, nll);
  loss_kernel<<<dim3(1), dim3(256), 0, stream>>>(nll, out + (size_t)NTOK * NV);
}

// Round 6
// 2380.110 us; speedup vs baseline: 6.1929x; 1.0352x over previous
//
#include <hip/hip_runtime.h>
#include <hip/hip_bf16.h>
#include <cstdint>
#include <cstddef>

#define NB 4
#define NT 1024
#define NE 768
#define NH 12
#define NHS 64
#define NL 6
#define NFF 3072
#define NV 50257
#define NVP 50304          // 50257 padded to /128
#define NTOK (NB*NT)       // 4096
#define NCB_LM (NVP/128)   // 393 col-blocks in LM head
#define QKVS 2304          // fused QKV row stride

typedef __attribute__((ext_vector_type(8))) short short8;
typedef __attribute__((ext_vector_type(4))) float f32x4;
typedef __hip_bfloat16 bf16;

// ---------------- embedding ----------------
__global__ __launch_bounds__(256) void embed_kernel(
    const int* __restrict__ idx, const float* __restrict__ tok,
    const float* __restrict__ pos, float* __restrict__ x)
{
  int bt = blockIdx.x;
  int token = idx[bt];
  int t = bt & (NT - 1);
  const float* tr = tok + (size_t)token * NE;
  const float* pr = pos + (size_t)t * NE;
  float* xr = x + (size_t)bt * NE;
  for (int i = threadIdx.x; i < NE; i += 256)
    xr[i] = tr[i] + pr[i];
}

// ---------------- layernorm (row = 768), bf16 out ----------------
__global__ __launch_bounds__(256) void ln_kernel(
    const float* __restrict__ in, const float* __restrict__ sc,
    const float* __restrict__ bi, bf16* __restrict__ out)
{
  int row = blockIdx.x, tid = threadIdx.x;
  const float* xr = in + (size_t)row * NE;
  float v0 = xr[tid], v1 = xr[tid + 256], v2 = xr[tid + 512];
  float s = v0 + v1 + v2;
  float ss = v0 * v0 + v1 * v1 + v2 * v2;
  #pragma unroll
  for (int o = 32; o > 0; o >>= 1) {
    s  += __shfl_xor(s, o);
    ss += __shfl_xor(ss, o);
  }
  __shared__ float r1[4], r2[4];
  if ((tid & 63) == 0) { r1[tid >> 6] = s; r2[tid >> 6] = ss; }
  __syncthreads();
  float tot = r1[0] + r1[1] + r1[2] + r1[3];
  float tss = r2[0] + r2[1] + r2[2] + r2[3];
  float mu  = tot * (1.f / NE);
  float var = tss * (1.f / NE) - mu * mu;
  float rs  = rsqrtf(var + 1e-5f);
  bf16* orow = out + (size_t)row * NE;
  orow[tid]       = __float2bfloat16((v0 - mu) * rs * sc[tid]       + bi[tid]);
  orow[tid + 256] = __float2bfloat16((v1 - mu) * rs * sc[tid + 256] + bi[tid + 256]);
  orow[tid + 512] = __float2bfloat16((v2 - mu) * rs * sc[tid + 512] + bi[tid + 512]);
}

// ------- transpose+convert: src f32 [R][Cs] (per z) -> dst bf16 [Cd][R] -------
__global__ __launch_bounds__(256) void tconv_kernel(
    const float* __restrict__ src, bf16* __restrict__ dst,
    int R, int Cs, int Cd)
{
  __shared__ float t[32][33];
  int z = blockIdx.z;
  src += (size_t)z * R * Cs;
  dst += (size_t)z * Cd * R;
  int c0 = blockIdx.x * 32, r0 = blockIdx.y * 32;
  int tx = threadIdx.x & 31, ty = threadIdx.x >> 5;
  #pragma unroll
  for (int i = 0; i < 32; i += 8) {
    int r = r0 + ty + i, c = c0 + tx;
    t[ty + i][tx] = (c < Cs) ? src[(size_t)r * Cs + c] : 0.f;
  }
  __syncthreads();
  #pragma unroll
  for (int i = 0; i < 32; i += 8) {
    int c = c0 + ty + i, r = r0 + tx;
    if (c < Cd) dst[(size_t)c * R + r] = __float2bfloat16(t[tx][ty + i]);
  }
}

// ---------------- bf16 MFMA GEMM (m97 structure + T2 LDS XOR-swizzle) ----------------
// x = col tile (fastest), y = row tile. MREP: row-frags per wave (4 -> BM=128, 2 -> BM=64).
// NTST: non-temporal f32 C stores (LM head: keeps B L3-resident under the logit stream).
// Optional fused per-row sum-exp partials (ps, M=0 shift; logits are O(5), f32-safe).
template<int MREP, bool NTST>
__global__ __launch_bounds__(256) void gemm_bf(
    const bf16* __restrict__ A,
    const bf16* __restrict__ BT,
    float* __restrict__ Cf, bf16* __restrict__ Cbf,
    const float* __restrict__ bias, const float* __restrict__ Rres,
    float* __restrict__ ps,
    int M, int N, int K, int relu, int ncb)
{
  constexpr int BMT = MREP * 32;
  __shared__ bf16 As[BMT][64];
  __shared__ bf16 Bs[128][64];
  __shared__ float ps2[BMT][2];
  int tid = threadIdx.x;
  int lane = tid & 63;
  int w = __builtin_amdgcn_readfirstlane(tid >> 6);
  int wr = w >> 1, wc = w & 1;
  int row0 = blockIdx.y * BMT;
  int col0 = blockIdx.x * 128;

  f32x4 acc[MREP][4] = {};

  for (int k0 = 0; k0 < K; k0 += 64) {
    #pragma unroll
    for (int r = 0; r < MREP; ++r) {       // A: BMT*8 16B-chunks
      int c = r * 256 + tid;
      int trow = c >> 3;
      int schunk = (c & 7) ^ (trow & 7);    // pre-swizzled source chunk
      const bf16* ga = A + (size_t)(row0 + trow) * K + k0 + (schunk << 3);
      __builtin_amdgcn_global_load_lds(
          (const __attribute__((address_space(1))) void*)ga,
          (__attribute__((address_space(3))) void*)((char*)&As[0][0] + (unsigned)c * 16),
          16, 0, 0);
    }
    #pragma unroll
    for (int r = 0; r < 4; ++r) {          // B: 1024 chunks
      int c = r * 256 + tid;
      int trow = c >> 3;
      int schunk = (c & 7) ^ (trow & 7);
      const bf16* gb = BT + (size_t)(col0 + trow) * K + k0 + (schunk << 3);
      __builtin_amdgcn_global_load_lds(
          (const __attribute__((address_space(1))) void*)gb,
          (__attribute__((address_space(3))) void*)((char*)&Bs[0][0] + (unsigned)c * 16),
          16, 0, 0);
    }
    __syncthreads();
    int l15 = lane & 15;
    int g8 = (lane >> 4) << 3;
    int sx = (l15 & 7) << 3;                // read-side swizzle
    #pragma unroll
    for (int kk = 0; kk < 64; kk += 32) {
      short8 a[MREP], b[4];
      #pragma unroll
      for (int m = 0; m < MREP; ++m)
        a[m] = *(const short8*)&As[wr * (MREP * 16) + m * 16 + l15][(kk + g8) ^ sx];
      #pragma unroll
      for (int n = 0; n < 4; ++n)
        b[n] = *(const short8*)&Bs[wc * 64 + n * 16 + l15][(kk + g8) ^ sx];
      #pragma unroll
      for (int m = 0; m < MREP; ++m)
        #pragma unroll
        for (int n = 0; n < 4; ++n)
          acc[m][n] = __builtin_amdgcn_mfma_f32_16x16x32_bf16(a[m], b[n], acc[m][n], 0, 0, 0);
    }
    __syncthreads();
  }

  int cr = lane >> 4;
  int cc = lane & 15;
  #pragma unroll
  for (int m = 0; m < MREP; ++m) {
    #pragma unroll
    for (int n = 0; n < 4; ++n) {
      int col = col0 + wc * 64 + n * 16 + cc;
      if (col >= N) continue;
      float bv = bias ? bias[col] : 0.f;
      #pragma unroll
      for (int e = 0; e < 4; ++e) {
        int row = row0 + wr * (MREP * 16) + m * 16 + cr * 4 + e;
        float v = acc[m][n][e] + bv;
        size_t off = (size_t)row * N + col;
        if (Rres) v += Rres[off];
        if (relu) v = fmaxf(v, 0.f);
        if (Cf) {
          if (NTST) __builtin_nontemporal_store(v, &Cf[off]);
          else      Cf[off] = v;
        }
        if (Cbf) Cbf[off] = __float2bfloat16(v);
      }
    }
  }

  // fused per-row sum-exp partials (no max shift) over this block's 128 cols
  if (ps) {
    #pragma unroll
    for (int m = 0; m < MREP; ++m) {
      #pragma unroll
      for (int e = 0; e < 4; ++e) {
        float ssum = 0.f;
        #pragma unroll
        for (int n = 0; n < 4; ++n) {
          int col = col0 + wc * 64 + n * 16 + cc;
          float val = (col < N) ? (acc[m][n][e] + (bias ? bias[col] : 0.f)) : -1e30f;
          ssum += __expf(val);
        }
        ssum += __shfl_xor(ssum, 1);
        ssum += __shfl_xor(ssum, 2);
        ssum += __shfl_xor(ssum, 4);
        ssum += __shfl_xor(ssum, 8);
        if (cc == 0) {
          int rl = wr * (MREP * 16) + m * 16 + cr * 4 + e;
          ps2[rl][wc] = ssum;
        }
      }
    }
    __syncthreads();
    for (int i = tid; i < BMT; i += 256) {
      size_t o = (size_t)(row0 + i) * ncb + blockIdx.x;
      ps[o] = ps2[i][0] + ps2[i][1];
    }
  }
}

// ---------------- flash attention, MFMA, online softmax ----------------
static __device__ inline unsigned short bfbits(float x) {
  bf16 h = __float2bfloat16(x);
  return *reinterpret_cast<unsigned short*>(&h);
}

__global__ __launch_bounds__(256) void fattn_kernel(
    const bf16* __restrict__ QKV, bf16* __restrict__ O)
{
  __shared__ unsigned short Ks[64][72];
  __shared__ unsigned short Vt[64][72];
  __shared__ unsigned short Pl[4][16][72];
  int qt = blockIdx.x, h = blockIdx.y, b = blockIdx.z;
  int tid = threadIdx.x;
  int lane = tid & 63;
  int w = tid >> 6;
  int l15 = lane & 15, g = lane >> 4;
  int brow = b * NT;
  int qbase = qt * 64;
  int q_loc = w * 16 + l15;

  short8 bq[2];
  {
    const bf16* qp = QKV + (size_t)(brow + qbase + q_loc) * QKVS + h * 64 + g * 8;
    bq[0] = *(const short8*)qp;
    bq[1] = *(const short8*)(qp + 32);
  }

  float m_run = -1e30f, l_run = 0.f;
  f32x4 acc[4] = {};

  for (int kt = 0; kt <= qt; ++kt) {
    int s0 = kt * 64;
    #pragma unroll
    for (int i = 0; i < 2; ++i) {
      int c = tid + i * 256;
      int row = c >> 3, colg = (c & 7) * 8;
      const bf16* kp = QKV + (size_t)(brow + s0 + row) * QKVS + NE + h * 64 + colg;
      const bf16* vp = QKV + (size_t)(brow + s0 + row) * QKVS + 2 * NE + h * 64 + colg;
      short8 kv = *(const short8*)kp;
      short8 vv = *(const short8*)vp;
      *(short8*)&Ks[row][colg] = kv;
      #pragma unroll
      for (int j = 0; j < 8; ++j)
        Vt[colg + j][row] = (unsigned short)vv[j];
    }
    __syncthreads();

    f32x4 sf[4] = {};
    #pragma unroll
    for (int kk = 0; kk < 2; ++kk) {
      #pragma unroll
      for (int m = 0; m < 4; ++m) {
        short8 a = *(const short8*)&Ks[m * 16 + l15][kk * 32 + g * 8];
        sf[m] = __builtin_amdgcn_mfma_f32_16x16x32_bf16(a, bq[kk], sf[m], 0, 0, 0);
      }
    }

    float sv[4][4];
    float mx = -1e30f;
    bool diag = (kt == qt);
    #pragma unroll
    for (int m = 0; m < 4; ++m)
      #pragma unroll
      for (int e = 0; e < 4; ++e) {
        float v = sf[m][e] * 0.125f;
        if (diag) {
          int sl = m * 16 + g * 4 + e;
          if (sl > q_loc) v = -1e30f;
        }
        sv[m][e] = v;
        mx = fmaxf(mx, v);
      }
    mx = fmaxf(mx, __shfl_xor(mx, 16));
    mx = fmaxf(mx, __shfl_xor(mx, 32));
    float m_new = fmaxf(m_run, mx);
    float p[4][4];
    float rs = 0.f;
    #pragma unroll
    for (int m = 0; m < 4; ++m)
      #pragma unroll
      for (int e = 0; e < 4; ++e) {
        float pe = __expf(sv[m][e] - m_new);
        p[m][e] = pe;
        rs += pe;
      }
    rs += __shfl_xor(rs, 16);
    rs += __shfl_xor(rs, 32);
    float sc_old = __expf(m_run - m_new);
    l_run = l_run * sc_old + rs;
    m_run = m_new;
    #pragma unroll
    for (int dm = 0; dm < 4; ++dm)
      #pragma unroll
      for (int e = 0; e < 4; ++e)
        acc[dm][e] *= sc_old;

    #pragma unroll
    for (int m = 0; m < 4; ++m)
      #pragma unroll
      for (int ep = 0; ep < 2; ++ep) {
        unsigned u = (unsigned)bfbits(p[m][2 * ep]) |
                     ((unsigned)bfbits(p[m][2 * ep + 1]) << 16);
        *(unsigned*)&Pl[w][l15][m * 16 + g * 4 + ep * 2] = u;
      }

    #pragma unroll
    for (int ks = 0; ks < 2; ++ks) {
      short8 pb = *(const short8*)&Pl[w][l15][ks * 32 + g * 8];
      #pragma unroll
      for (int dm = 0; dm < 4; ++dm) {
        short8 av = *(const short8*)&Vt[dm * 16 + l15][ks * 32 + g * 8];
        acc[dm] = __builtin_amdgcn_mfma_f32_16x16x32_bf16(av, pb, acc[dm], 0, 0, 0);
      }
    }
    __syncthreads();
  }

  float inv = 1.f / l_run;
  bf16* op = O + (size_t)(brow + qbase + q_loc) * NE + h * 64;
  #pragma unroll
  for (int dm = 0; dm < 4; ++dm)
    #pragma unroll
    for (int ep = 0; ep < 2; ++ep) {
      int d = dm * 16 + g * 4 + ep * 2;
      unsigned u = (unsigned)bfbits(acc[dm][2 * ep] * inv) |
                   ((unsigned)bfbits(acc[dm][2 * ep + 1] * inv) << 16);
      *(unsigned*)((unsigned short*)op + d) = u;
    }
}

// ---------------- NLL from fused sum-exp partials (M=0 shift) ----------------
__global__ __launch_bounds__(128) void nll_finish(
    const float* __restrict__ ps,
    const float* __restrict__ logits, const int* __restrict__ targets,
    float* __restrict__ nll)
{
  int row = blockIdx.x, tid = threadIdx.x;
  float s = 0.f;
  for (int i = tid; i < NCB_LM; i += 128)
    s += ps[(size_t)row * NCB_LM + i];
  #pragma unroll
  for (int o = 32; o > 0; o >>= 1) s += __shfl_xor(s, o);
  __shared__ float ss[2];
  if ((tid & 63) == 0) ss[tid >> 6] = s;
  __syncthreads();
  if (tid == 0) {
    float S = ss[0] + ss[1];
    float tgt = logits[(size_t)row * NV + targets[row]];
    nll[row] = logf(S) - tgt;
  }
}

__global__ __launch_bounds__(256) void loss_kernel(
    const float* __restrict__ nll, float* __restrict__ out)
{
  int tid = threadIdx.x;
  float s = 0.f;
  for (int i = tid; i < NTOK; i += 256) s += nll[i];
  #pragma unroll
  for (int o = 32; o > 0; o >>= 1) s += __shfl_xor(s, o);
  __shared__ float red[4];
  if ((tid & 63) == 0) red[tid >> 6] = s;
  __syncthreads();
  if (tid == 0) out[0] = (red[0] + red[1] + red[2] + red[3]) * (1.f / NTOK);
}

// ---------------- host ----------------
static inline void gemm(const bf16* A, const bf16* BT,
                        float* Cf, bf16* Cbf,
                        const float* bias, const float* Rres, float* ps,
                        int M, int N, int Npad, int K, int relu,
                        int mrep, bool ntst, hipStream_t st)
{
  int ncb = Npad / 128;
  dim3 g(ncb, M / (mrep * 32));
  if (mrep == 4) {
    if (ntst)
      gemm_bf<4, true><<<g, dim3(256), 0, st>>>(A, BT, Cf, Cbf, bias, Rres, ps, M, N, K, relu, ncb);
    else
      gemm_bf<4, false><<<g, dim3(256), 0, st>>>(A, BT, Cf, Cbf, bias, Rres, ps, M, N, K, relu, ncb);
  } else {
    gemm_bf<2, false><<<g, dim3(256), 0, st>>>(A, BT, Cf, Cbf, bias, Rres, ps, M, N, K, relu, ncb);
  }
}

extern "C" void kernel_launch(void* const* d_in, const int* in_sizes, int n_in,
                              void* d_out, int out_size, void* d_ws, size_t ws_size,
                              hipStream_t stream)
{
  const int*   idx     = (const int*)  d_in[0];
  const int*   targets = (const int*)  d_in[1];
  const float* tok_emb = (const float*)d_in[2];
  const float* pos_emb = (const float*)d_in[3];
  const float* Wq      = (const float*)d_in[4];
  const float* Wk      = (const float*)d_in[5];
  const float* Wv      = (const float*)d_in[6];
  const float* Wo      = (const float*)d_in[7];
  const float* bo      = (const float*)d_in[8];
  const float* ln1_s   = (const float*)d_in[9];
  const float* ln1_b   = (const float*)d_in[10];
  const float* ln2_s   = (const float*)d_in[11];
  const float* ln2_b   = (const float*)d_in[12];
  const float* W1      = (const float*)d_in[13];
  const float* b1      = (const float*)d_in[14];
  const float* W2      = (const float*)d_in[15];
  const float* b2      = (const float*)d_in[16];
  const float* lnf_s   = (const float*)d_in[17];
  const float* lnf_b   = (const float*)d_in[18];
  const float* Wlm     = (const float*)d_in[19];
  const float* blm     = (const float*)d_in[20];
  float* out = (float*)d_out;

  const size_t XE = (size_t)NTOK * NE;
  char* p = (char*)d_ws;
  float* x     = (float*)p;         p += XE * 4;
  bf16* h_bf   = (bf16*)p;          p += XE * 2;
  bf16* qkv_bf = (bf16*)p;          p += (size_t)NTOK * QKVS * 2;
  bf16* att_bf = (bf16*)p;          p += XE * 2;
  bf16* f_bf   = (bf16*)p;          p += (size_t)NTOK * NFF * 2;
  bf16* wqkv   = (bf16*)p;          p += (size_t)QKVS * NE * 2;
  bf16* wto    = (bf16*)p;          p += (size_t)NE * NE * 2;
  bf16* wt1    = (bf16*)p;          p += (size_t)NFF * NE * 2;
  bf16* wt2    = (bf16*)p;          p += (size_t)NE * NFF * 2;
  bf16* wtlm   = (bf16*)p;          p += (size_t)NVP * NE * 2;
  float* psb   = (float*)p;         p += (size_t)NTOK * NCB_LM * 4;
  float* nll   = (float*)p;         p += (size_t)NTOK * 4;

  embed_kernel<<<dim3(NTOK), dim3(256), 0, stream>>>(idx, tok_emb, pos_emb, x);

  for (int l = 0; l < NL; ++l) {
    const float* wq_l = Wq + (size_t)l * NH * NE * NHS;
    const float* wk_l = Wk + (size_t)l * NH * NE * NHS;
    const float* wv_l = Wv + (size_t)l * NH * NE * NHS;
    const float* wo_l = Wo + (size_t)l * NE * NE;
    const float* w1_l = W1 + (size_t)l * NE * NFF;
    const float* w2_l = W2 + (size_t)l * NFF * NE;

    ln_kernel<<<dim3(NTOK), dim3(256), 0, stream>>>(x, ln1_s + l*NE, ln1_b + l*NE, h_bf);

    // fused QKV weight: rows 0..767 = Q, 768..1535 = K, 1536..2303 = V
    tconv_kernel<<<dim3(2, 24, NH), dim3(256), 0, stream>>>(wq_l, wqkv, NE, NHS, NHS);
    tconv_kernel<<<dim3(2, 24, NH), dim3(256), 0, stream>>>(wk_l, wqkv + (size_t)NE*NE, NE, NHS, NHS);
    tconv_kernel<<<dim3(2, 24, NH), dim3(256), 0, stream>>>(wv_l, wqkv + (size_t)2*NE*NE, NE, NHS, NHS);
    tconv_kernel<<<dim3(24, 24, 1), dim3(256), 0, stream>>>(wo_l, wto, NE, NE, NE);
    tconv_kernel<<<dim3(96, 24, 1), dim3(256), 0, stream>>>(w1_l, wt1, NE, NFF, NFF);
    tconv_kernel<<<dim3(24, 96, 1), dim3(256), 0, stream>>>(w2_l, wt2, NFF, NE, NE);

    gemm(h_bf, wqkv, nullptr, qkv_bf, nullptr, nullptr, nullptr,
         NTOK, QKVS, QKVS, NE, 0, 4, false, stream);

    fattn_kernel<<<dim3(NT / 64, NH, NB), dim3(256), 0, stream>>>(qkv_bf, att_bf);

    gemm(att_bf, wto, x, nullptr, bo + l*NE, x, nullptr,
         NTOK, NE, NE, NE, 0, 2, false, stream);

    ln_kernel<<<dim3(NTOK), dim3(256), 0, stream>>>(x, ln2_s + l*NE, ln2_b + l*NE, h_bf);

    gemm(h_bf, wt1, nullptr, f_bf, b1 + l*NFF, nullptr, nullptr,
         NTOK, NFF, NFF, NE, 1, 4, false, stream);
    gemm(f_bf, wt2, x, nullptr, b2 + l*NE, x, nullptr,
         NTOK, NE, NE, NFF, 0, 2, false, stream);
  }

  ln_kernel<<<dim3(NTOK), dim3(256), 0, stream>>>(x, lnf_s, lnf_b, h_bf);
  tconv_kernel<<<dim3(NVP/32, 24, 1), dim3(256), 0, stream>>>(Wlm, wtlm, NE, NV, NVP);
  gemm(h_bf, wtlm, out, nullptr, blm, nullptr, psb,
       NTOK, NV, NVP, NE, 0, 4, true, stream);

  nll_finish<<<dim3(NTOK), dim3(128), 0, stream>>>(psb, out, targets, nll);
  loss_kernel<<<dim3(1), dim3(256), 0, stream>>>(nll, out + (size_t)NTOK * NV);
}